// Round 11
// baseline (373.318 us; speedup 1.0000x reference)
//
#include <hip/hip_runtime.h>
#include <hip/hip_bf16.h>
#include <math.h>

// Sizes: B=16, N=64, nE=128, H=128, LAT=128, NS=64, NV=32, INV=96, D_NODE=160
#define SQRT3F 1.7320508075688772f
#define ALPHAF 0.10206207261596577f  // 1/sqrt(96)
#define PIF 3.14159265358979323846f

typedef short v8s __attribute__((ext_vector_type(8)));
typedef float v4f __attribute__((ext_vector_type(4)));

__device__ __forceinline__ float silu_f(float x) {
  return x / (1.0f + __expf(-x));
}
__device__ __forceinline__ float sigmoid_f(float x) {
  return 1.0f / (1.0f + __expf(-x));
}
__device__ __forceinline__ unsigned short f2bf(float f) {
  unsigned int u = __float_as_uint(f);
  unsigned int r = (u + 0x7fffu + ((u >> 16) & 1u)) >> 16;
  return (unsigned short)r;
}
__device__ __forceinline__ float bf2f(unsigned short h) {
  return __uint_as_float(((unsigned int)h) << 16);
}

// ---------------------------------------------------------------------------
// K-1 v2: cast W2 (128 x 9216 fp32) into MFMA B-FRAGMENT order, bf16 hi/lo.
// ---------------------------------------------------------------------------
__global__ void __launch_bounds__(256) k_castw2(
    const float* __restrict__ W2, unsigned short* __restrict__ W2fh,
    unsigned short* __restrict__ W2fl) {
  const int T = blockIdx.x;           // column tile of 16
  const int tid = threadIdx.x;
  __shared__ float Tl[128][17];

  for (int idx = tid; idx < 2048; idx += 256) {
    int k = idx >> 4, cc = idx & 15;
    Tl[k][cc] = W2[(size_t)k * 9216 + T * 16 + cc];
  }
  __syncthreads();

  const int ks = tid >> 6, lane = tid & 63;
  const int q = lane >> 4, cq = lane & 15;
  const int k0 = ks * 32 + q * 8;
  unsigned short hv[8], lv[8];
  #pragma unroll
  for (int j = 0; j < 8; ++j) {
    float wv = Tl[k0 + j][cq];
    unsigned short h = f2bf(wv);
    hv[j] = h;
    lv[j] = f2bf(wv - bf2f(h));
  }
  size_t base = ((size_t)(T * 4 + ks) * 64 + lane) * 8;
  *(uint4*)&W2fh[base] = *(uint4*)hv;
  *(uint4*)&W2fl[base] = *(uint4*)lv;
}

// ---------------------------------------------------------------------------
// K-2: pack sc_W1 (128x128) into MFMA B-fragment order, bf16 hi/lo.
// ---------------------------------------------------------------------------
__global__ void __launch_bounds__(256) k_castw1(
    const float* __restrict__ W1, unsigned short* __restrict__ W1fh,
    unsigned short* __restrict__ W1fl) {
  const int s = blockIdx.x * 256 + threadIdx.x;   // 0..2047
  const int lane = s & 63;
  const int t = (s >> 6) & 7;
  const int ks = s >> 9;
  const int kbase = ks * 32 + (lane >> 4) * 8;
  const int n = t * 16 + (lane & 15);
  unsigned short hv[8], lv[8];
  #pragma unroll
  for (int j = 0; j < 8; ++j) {
    float w = W1[(size_t)(kbase + j) * 128 + n];
    unsigned short h = f2bf(w);
    hv[j] = h;
    lv[j] = f2bf(w - bf2f(h));
  }
  *(uint4*)&W1fh[(size_t)s * 8] = *(uint4*)hv;
  *(uint4*)&W1fl[(size_t)s * 8] = *(uint4*)lv;
}

// ---------------------------------------------------------------------------
// K0: per-node prep, 4 nodes per block. grid=256, block=128.
// ---------------------------------------------------------------------------
__global__ void k_prep(const float* __restrict__ hf, const int* __restrict__ z,
                       const float* __restrict__ pos, const float* __restrict__ z_emb,
                       const float* __restrict__ vwW0, const float* __restrict__ vwb0,
                       const float* __restrict__ vwW1, const float* __restrict__ vwb1,
                       const float* __restrict__ scW0,
                       unsigned short* __restrict__ hTh, unsigned short* __restrict__ hTl,
                       float* __restrict__ Pn, float* __restrict__ Pa,
                       float* __restrict__ xvu, float* __restrict__ y1cw) {
  const int g0 = blockIdx.x * 4;
  const int b = g0 >> 6;
  const int t = threadIdx.x;

  __shared__ float vin[4][64];
  __shared__ float invn[4][96];
  __shared__ float h0[4][128];
  __shared__ float uS[4][3];
  __shared__ float rS[4];

  if (t < 4) {
    const int g = g0 + t;
    float px = pos[g * 3 + 0] - pos[(b * 64) * 3 + 0];
    float py = pos[g * 3 + 1] - pos[(b * 64) * 3 + 1];
    float pz = pos[g * 3 + 2] - pos[(b * 64) * 3 + 2];
    float r = sqrtf(px * px + py * py + pz * pz + 1e-12f);
    float rm = fmaxf(r, 1e-8f);
    uS[t][0] = px / rm; uS[t][1] = py / rm; uS[t][2] = pz / rm;
    rS[t] = r;
  }
  __syncthreads();

  if (t < 32) {
    const float delta = 6.0f / 31.0f;
    const float gamma = 1.0f / (delta * delta + 1e-12f);
    #pragma unroll
    for (int nn = 0; nn < 4; ++nn) {
      int zi = z[g0 + nn];
      vin[nn][t] = z_emb[zi * 32 + t];
      float rc = fminf(rS[nn], 6.0f);
      float d = rc - (float)t * delta;
      vin[nn][32 + t] = __expf(-gamma * d * d);
      float a = hf[(g0 + nn) * 160 + 64 + t * 3 + 0] * uS[nn][0]
              + hf[(g0 + nn) * 160 + 64 + t * 3 + 1] * uS[nn][1]
              + hf[(g0 + nn) * 160 + 64 + t * 3 + 2] * uS[nn][2];
      xvu[(g0 + nn) * 32 + t] = a;
    }
  }
  if (t < 96) {
    #pragma unroll
    for (int nn = 0; nn < 4; ++nn) {
      const int g = g0 + nn;
      if (t < 64) {
        invn[nn][t] = hf[g * 160 + t];
      } else {
        int o = t - 64;
        float v0 = hf[g * 160 + 64 + o * 3 + 0];
        float v1 = hf[g * 160 + 64 + o * 3 + 1];
        float v2 = hf[g * 160 + 64 + o * 3 + 2];
        invn[nn][t] = sqrtf((v0 * v0 + v1 * v1 + v2 * v2) * (1.0f / 3.0f) + 1e-8f);
      }
    }
  }
  if (t < 4) {
    const int n = (g0 + t) & 63;
    float r = rS[t];
    float cw = 0.0f;
    if (r <= 6.0f && n != 0) cw = 0.5f * (cosf(PIF * r * (1.0f / 6.0f)) + 1.0f);
    y1cw[(g0 + t) * 4 + 0] = SQRT3F * uS[t][0];
    y1cw[(g0 + t) * 4 + 1] = SQRT3F * uS[t][1];
    y1cw[(g0 + t) * 4 + 2] = SQRT3F * uS[t][2];
    y1cw[(g0 + t) * 4 + 3] = cw;
  }
  __syncthreads();

  {
    float a0 = vwb0[t], a1 = a0, a2 = a0, a3 = a0;
    #pragma unroll 8
    for (int k = 0; k < 64; ++k) {
      float w = vwW0[k * 128 + t];
      a0 = fmaf(vin[0][k], w, a0);
      a1 = fmaf(vin[1][k], w, a1);
      a2 = fmaf(vin[2][k], w, a2);
      a3 = fmaf(vin[3][k], w, a3);
    }
    h0[0][t] = silu_f(a0); h0[1][t] = silu_f(a1);
    h0[2][t] = silu_f(a2); h0[3][t] = silu_f(a3);
  }
  __syncthreads();
  {
    float a0 = vwb1[t], a1 = a0, a2 = a0, a3 = a0;
    #pragma unroll 8
    for (int k = 0; k < 128; ++k) {
      float w = vwW1[k * 128 + t];
      a0 = fmaf(h0[0][k], w, a0);
      a1 = fmaf(h0[1][k], w, a1);
      a2 = fmaf(h0[2][k], w, a2);
      a3 = fmaf(h0[3][k], w, a3);
    }
    float hv[4] = {silu_f(a0), silu_f(a1), silu_f(a2), silu_f(a3)};
    #pragma unroll
    for (int nn = 0; nn < 4; ++nn) {
      unsigned short hh = f2bf(hv[nn]);
      hTh[(size_t)(g0 + nn) * 128 + t] = hh;
      hTl[(size_t)(g0 + nn) * 128 + t] = f2bf(hv[nn] - bf2f(hh));
    }
  }
  {
    float p0 = 0.f, p1 = 0.f, p2 = 0.f, p3 = 0.f;
    #pragma unroll 8
    for (int k = 0; k < 96; ++k) {
      float w = scW0[(96 + k) * 128 + t];
      p0 = fmaf(invn[0][k], w, p0);
      p1 = fmaf(invn[1][k], w, p1);
      p2 = fmaf(invn[2][k], w, p2);
      p3 = fmaf(invn[3][k], w, p3);
    }
    #pragma unroll 8
    for (int k = 0; k < 64; ++k) {
      float w = scW0[(192 + k) * 128 + t];
      p0 = fmaf(vin[0][k], w, p0);
      p1 = fmaf(vin[1][k], w, p1);
      p2 = fmaf(vin[2][k], w, p2);
      p3 = fmaf(vin[3][k], w, p3);
    }
    Pn[(g0 + 0) * 128 + t] = p0;
    Pn[(g0 + 1) * 128 + t] = p1;
    Pn[(g0 + 2) * 128 + t] = p2;
    Pn[(g0 + 3) * 128 + t] = p3;
  }
  if ((g0 & 63) == 0) {
    float p = 0.0f;
    #pragma unroll 8
    for (int k = 0; k < 96; ++k) p = fmaf(invn[0][k], scW0[k * 128 + t], p);
    Pa[b * 128 + t] = p;
  }
}

// ---------------------------------------------------------------------------
// KPe: Pe[e][t] = sc_b0[t] + e_feat[e]@We. grid=128, block=128.
// ---------------------------------------------------------------------------
__global__ void k_pe(const float* __restrict__ e_feat, const float* __restrict__ scW0,
                     const float* __restrict__ scb0, float* __restrict__ Pe) {
  const int e = blockIdx.x;
  const int t = threadIdx.x;
  float a = scb0[t];
  #pragma unroll
  for (int k = 0; k < 16; ++k) a = fmaf(e_feat[e * 16 + k], scW0[(256 + k) * 128 + t], a);
  Pe[e * 128 + t] = a;
}

// ---------------------------------------------------------------------------
// K2 v11: MFMA GEMM + register contraction. K-SPLIT 2 + depth-2 prefetch.
// grid = 1024: ch = bid&7 (XCD-aligned), ks2 = (bid>>3)&1 (K half),
// g0 = (bid>>4)*16. R10 lesson: grid 512 capped occupancy at 2 blocks/CU —
// pure latency wall (MfmaUtil 4%, nothing busy). Now 4 blocks/CU, half work
// per tile, 3 BF in flight. Bias added only by ks2==0 (tp is linear in K).
// ---------------------------------------------------------------------------
struct BF2 {
  v8s h0, h1, l0, l1;
  float bias;
};

__device__ __forceinline__ BF2 load_bf2(const unsigned short* __restrict__ W2fh,
                                        const unsigned short* __restrict__ W2fl,
                                        const float* __restrict__ b2,
                                        int T, int ks2, int l, int cq) {
  BF2 f;
  const size_t base = (size_t)T * 2048 + (size_t)ks2 * 1024 + (size_t)l * 8;
  f.h0 = *(const v8s*)(W2fh + base);
  f.h1 = *(const v8s*)(W2fh + base + 512);
  f.l0 = *(const v8s*)(W2fl + base);
  f.l1 = *(const v8s*)(W2fl + base + 512);
  f.bias = b2[T * 16 + cq];
  return f;
}

__global__ void __launch_bounds__(256, 4) k_tp(
    const unsigned short* __restrict__ hTh, const unsigned short* __restrict__ hTl,
    const unsigned short* __restrict__ W2fh, const unsigned short* __restrict__ W2fl,
    const float* __restrict__ b2, const float* __restrict__ hf,
    const float* __restrict__ xvu, const float* __restrict__ y1cw,
    float* __restrict__ values) {
  const int bid = blockIdx.x;
  const int ch = bid & 7;             // XCD-aligned col split
  const int ks2 = (bid >> 3) & 1;     // K half
  const int g0 = (bid >> 4) * 16;     // node tile
  const int tid = threadIdx.x;
  const int w = tid >> 6, l = tid & 63;
  const int q = l >> 4, cq = l & 15;
  const float bsc = (ks2 == 0) ? 1.0f : 0.0f;

  __shared__ float xsS[16][64];
  __shared__ float xvS[16][96];
  __shared__ float xvuS[16][32];
  __shared__ float y1S[16][4];
  __shared__ float valsS[16][160];
  __shared__ float svS[16][32];

  for (int idx = tid; idx < 16 * 64; idx += 256) {
    int n = idx >> 6, i = idx & 63;
    xsS[n][i] = hf[(size_t)(g0 + n) * 160 + i];
  }
  for (int idx = tid; idx < 16 * 96; idx += 256) {
    int n = idx / 96, k = idx - n * 96;
    xvS[n][k] = hf[(size_t)(g0 + n) * 160 + 64 + k];
  }
  for (int idx = tid; idx < 16 * 32; idx += 256) {
    int n = idx >> 5, i = idx & 31;
    xvuS[n][i] = xvu[(size_t)(g0 + n) * 32 + i];
  }
  if (tid < 64) ((float*)y1S)[tid] = y1cw[(size_t)g0 * 4 + tid];
  for (int idx = tid; idx < 16 * 160; idx += 256) ((float*)valsS)[idx] = 0.f;
  for (int idx = tid; idx < 16 * 32; idx += 256) ((float*)svS)[idx] = 0.f;

  // A fragments for this K-half: ks = ks2*2 + {0,1}
  v8s ah0 = *(const v8s*)&hTh[(size_t)(g0 + cq) * 128 + (ks2 * 2 + 0) * 32 + q * 8];
  v8s ah1 = *(const v8s*)&hTh[(size_t)(g0 + cq) * 128 + (ks2 * 2 + 1) * 32 + q * 8];
  v8s al0 = *(const v8s*)&hTl[(size_t)(g0 + cq) * 128 + (ks2 * 2 + 0) * 32 + q * 8];
  v8s al1 = *(const v8s*)&hTl[(size_t)(g0 + cq) * 128 + (ks2 * 2 + 1) * 32 + q * 8];
  __syncthreads();

  // 3 independent 2-chains (hh / lh / hl), summed at the end.
  #define TILE_MFMA2(f, outp)                                                  \
    {                                                                          \
      v4f a0_ = (v4f){0.f, 0.f, 0.f, 0.f};                                     \
      v4f a1_ = (v4f){0.f, 0.f, 0.f, 0.f};                                     \
      v4f a2_ = (v4f){0.f, 0.f, 0.f, 0.f};                                     \
      a0_ = __builtin_amdgcn_mfma_f32_16x16x32_bf16(ah0, (f).h0, a0_, 0, 0, 0);\
      a1_ = __builtin_amdgcn_mfma_f32_16x16x32_bf16(al0, (f).h0, a1_, 0, 0, 0);\
      a2_ = __builtin_amdgcn_mfma_f32_16x16x32_bf16(ah0, (f).l0, a2_, 0, 0, 0);\
      a0_ = __builtin_amdgcn_mfma_f32_16x16x32_bf16(ah1, (f).h1, a0_, 0, 0, 0);\
      a1_ = __builtin_amdgcn_mfma_f32_16x16x32_bf16(al1, (f).h1, a1_, 0, 0, 0);\
      a2_ = __builtin_amdgcn_mfma_f32_16x16x32_bf16(ah1, (f).l1, a2_, 0, 0, 0);\
      a0_ += a1_; a0_ += a2_;                                                  \
      float bb_ = (f).bias * bsc;                                              \
      a0_[0] += bb_; a0_[1] += bb_; a0_[2] += bb_; a0_[3] += bb_;              \
      outp = a0_;                                                              \
    }

  // ---- w1: 8 tiles/wave. T = ch*32 + w*8 + t; i=T>>2, o=(t&3)*16+cq ----
  {
    const int T0 = ch * 32 + w * 8;
    const int i0 = T0 >> 2;
    float racc[4][4] = {{0.f}};
    BF2 f0 = load_bf2(W2fh, W2fl, b2, T0, ks2, l, cq);
    BF2 f1 = load_bf2(W2fh, W2fl, b2, T0 + 1, ks2, l, cq);
    #pragma unroll
    for (int t = 0; t < 8; ++t) {
      BF2 fn;
      if (t < 6) fn = load_bf2(W2fh, W2fl, b2, T0 + t + 2, ks2, l, cq);
      v4f tp; TILE_MFMA2(f0, tp);
      const int ii = t >> 2, m = t & 3;
      #pragma unroll
      for (int r = 0; r < 4; ++r)
        racc[m][r] = fmaf(xsS[q * 4 + r][i0 + ii], tp[r], racc[m][r]);
      f0 = f1; f1 = fn;
    }
    #pragma unroll
    for (int m = 0; m < 4; ++m)
      #pragma unroll
      for (int r = 0; r < 4; ++r)
        atomicAdd(&valsS[q * 4 + r][m * 16 + cq], racc[m][r]);
  }

  // ---- w2: 4 tiles/wave. T = 256 + ch*16 + w*4 + t ----
  {
    const int T0 = 256 + ch * 16 + w * 4;
    const int i0 = (T0 - 256) >> 1;
    float racc[2][4] = {{0.f}};
    BF2 f0 = load_bf2(W2fh, W2fl, b2, T0, ks2, l, cq);
    BF2 f1 = load_bf2(W2fh, W2fl, b2, T0 + 1, ks2, l, cq);
    #pragma unroll
    for (int t = 0; t < 4; ++t) {
      BF2 fn;
      if (t < 2) fn = load_bf2(W2fh, W2fl, b2, T0 + t + 2, ks2, l, cq);
      v4f tp; TILE_MFMA2(f0, tp);
      const int ii = t >> 1, m = t & 1;
      #pragma unroll
      for (int r = 0; r < 4; ++r)
        racc[m][r] = fmaf(xsS[q * 4 + r][i0 + ii], tp[r], racc[m][r]);
      f0 = f1; f1 = fn;
    }
    #pragma unroll
    for (int m = 0; m < 2; ++m)
      #pragma unroll
      for (int r = 0; r < 4; ++r)
        atomicAdd(&svS[q * 4 + r][m * 16 + cq], racc[m][r]);
  }

  // ---- w3: 2 tiles/wave. T = 384 + ch*8 + w*2 + t ----
  {
    const int T0 = 384 + ch * 8 + w * 2;
    const int i0 = (T0 - 384) >> 1;
    float racc[2][4][3] = {{{0.f}}};
    BF2 f0 = load_bf2(W2fh, W2fl, b2, T0, ks2, l, cq);
    BF2 f1 = load_bf2(W2fh, W2fl, b2, T0 + 1, ks2, l, cq);
    #pragma unroll
    for (int t = 0; t < 2; ++t) {
      v4f tp;
      if (t == 0) { TILE_MFMA2(f0, tp); } else { TILE_MFMA2(f1, tp); }
      #pragma unroll
      for (int r = 0; r < 4; ++r)
        #pragma unroll
        for (int cc = 0; cc < 3; ++cc)
          racc[t][r][cc] = fmaf(xvS[q * 4 + r][3 * i0 + cc], tp[r], racc[t][r][cc]);
    }
    #pragma unroll
    for (int m = 0; m < 2; ++m)
      #pragma unroll
      for (int r = 0; r < 4; ++r)
        #pragma unroll
        for (int cc = 0; cc < 3; ++cc)
          atomicAdd(&valsS[q * 4 + r][64 + 3 * (m * 16 + cq) + cc], racc[m][r][cc]);
  }

  // ---- w4: 4 tiles/wave. T = 448 + ch*16 + w*4 + t ----
  {
    const int T0 = 448 + ch * 16 + w * 4;
    const int i0 = (T0 - 448) >> 2;
    float racc[4][4] = {{0.f}};
    BF2 f0 = load_bf2(W2fh, W2fl, b2, T0, ks2, l, cq);
    BF2 f1 = load_bf2(W2fh, W2fl, b2, T0 + 1, ks2, l, cq);
    #pragma unroll
    for (int t = 0; t < 4; ++t) {
      BF2 fn;
      if (t < 2) fn = load_bf2(W2fh, W2fl, b2, T0 + t + 2, ks2, l, cq);
      v4f tp; TILE_MFMA2(f0, tp);
      #pragma unroll
      for (int r = 0; r < 4; ++r)
        racc[t][r] = fmaf(xvuS[q * 4 + r][i0], tp[r], racc[t][r]);
      f0 = f1; f1 = fn;
    }
    #pragma unroll
    for (int m = 0; m < 4; ++m)
      #pragma unroll
      for (int r = 0; r < 4; ++r)
        atomicAdd(&valsS[q * 4 + r][m * 16 + cq], racc[m][r]);
  }
  #undef TILE_MFMA2
  __syncthreads();

  for (int idx = tid; idx < 2560; idx += 256) {
    int n = idx / 160, d = idx - n * 160;
    float v = valsS[n][d];
    if (d >= 64) {
      int dd = d - 64, o = dd / 3, cc = dd - 3 * o;
      v = fmaf(svS[n][o], y1S[n][cc], v);
    }
    atomicAdd(&values[(size_t)(g0 + n) * 160 + d], ALPHAF * v);
  }
}

// ---------------------------------------------------------------------------
// K3 v4: MFMA gate MLP + aggregation per (b,e). grid=2048, block=256.
// ---------------------------------------------------------------------------
__global__ void __launch_bounds__(256, 4) k_gate_agg(
    const float* __restrict__ Pa, const float* __restrict__ Pe,
    const float* __restrict__ Pn,
    const unsigned short* __restrict__ W1fh, const unsigned short* __restrict__ W1fl,
    const float* __restrict__ b1, const float* __restrict__ W2v,
    const float* __restrict__ b2s, const float* __restrict__ y1cw,
    const float* __restrict__ values, float* __restrict__ inv_agg) {
  const int bid = blockIdx.x;
  const int b = bid >> 7, e = bid & 127;
  const int tid = threadIdx.x;

  __shared__ float Prow[128];
  __shared__ float gpre[64];
  __shared__ float gateL[64];
  __shared__ float aggL[160];
  __shared__ float normS;

  if (tid < 128) Prow[tid] = Pa[b * 128 + tid] + Pe[e * 128 + tid];
  __syncthreads();

  const int w = tid >> 6, l = tid & 63;
  const int q = l >> 4, cq = l & 15;
  const int node = w * 16 + cq;
  const float* pnrow = Pn + (size_t)(b * 64 + node) * 128;

  v4f acc[8];
  #pragma unroll
  for (int t = 0; t < 8; ++t) acc[t] = (v4f){0.f, 0.f, 0.f, 0.f};

  #pragma unroll
  for (int ks = 0; ks < 4; ++ks) {
    const int k0 = ks * 32 + q * 8;
    float4 p0 = *(const float4*)(pnrow + k0);
    float4 p1 = *(const float4*)(pnrow + k0 + 4);
    float4 r0 = *(const float4*)(&Prow[k0]);
    float4 r1 = *(const float4*)(&Prow[k0 + 4]);
    float xv[8] = {p0.x + r0.x, p0.y + r0.y, p0.z + r0.z, p0.w + r0.w,
                   p1.x + r1.x, p1.y + r1.y, p1.z + r1.z, p1.w + r1.w};
    v8s avh, avl;
    #pragma unroll
    for (int j = 0; j < 8; ++j) {
      float x = silu_f(xv[j]);
      unsigned short h = f2bf(x);
      avh[j] = (short)h;
      avl[j] = (short)f2bf(x - bf2f(h));
    }
    #pragma unroll
    for (int t = 0; t < 8; ++t) {
      const size_t fb = (size_t)((ks * 8 + t) * 64 + l) * 8;
      v8s bh = *(const v8s*)&W1fh[fb];
      v8s bl = *(const v8s*)&W1fl[fb];
      acc[t] = __builtin_amdgcn_mfma_f32_16x16x32_bf16(avh, bh, acc[t], 0, 0, 0);
      acc[t] = __builtin_amdgcn_mfma_f32_16x16x32_bf16(avl, bh, acc[t], 0, 0, 0);
      acc[t] = __builtin_amdgcn_mfma_f32_16x16x32_bf16(avh, bl, acc[t], 0, 0, 0);
    }
  }

  float part0 = 0.f, part1 = 0.f, part2 = 0.f, part3 = 0.f;
  #pragma unroll
  for (int t = 0; t < 8; ++t) {
    float bb = b1[t * 16 + cq];
    float wg = W2v[t * 16 + cq];
    part0 = fmaf(silu_f(acc[t][0] + bb), wg, part0);
    part1 = fmaf(silu_f(acc[t][1] + bb), wg, part1);
    part2 = fmaf(silu_f(acc[t][2] + bb), wg, part2);
    part3 = fmaf(silu_f(acc[t][3] + bb), wg, part3);
  }
  #pragma unroll
  for (int off = 1; off < 16; off <<= 1) {
    part0 += __shfl_xor(part0, off);
    part1 += __shfl_xor(part1, off);
    part2 += __shfl_xor(part2, off);
    part3 += __shfl_xor(part3, off);
  }
  if (cq == 0) {
    gpre[w * 16 + q * 4 + 0] = part0;
    gpre[w * 16 + q * 4 + 1] = part1;
    gpre[w * 16 + q * 4 + 2] = part2;
    gpre[w * 16 + q * 4 + 3] = part3;
  }
  __syncthreads();

  if (tid < 64) {
    float gv = sigmoid_f(gpre[tid] + b2s[0]);
    gv *= y1cw[(b * 64 + tid) * 4 + 3];
    gateL[tid] = gv;
    float t2 = gv;
    #pragma unroll
    for (int off = 32; off > 0; off >>= 1) t2 += __shfl_down(t2, off);
    if (tid == 0) normS = fmaxf(t2, 1e-8f);
  }
  __syncthreads();

  if (tid < 160) {
    float a = 0.0f;
    const float* vp = values + (size_t)b * 64 * 160 + tid;
    #pragma unroll 4
    for (int n = 0; n < 64; ++n) a = fmaf(gateL[n], vp[n * 160], a);
    aggL[tid] = a / normS;
  }
  __syncthreads();
  if (tid < 96) {
    float rv;
    if (tid < 64) {
      rv = aggL[tid];
    } else {
      int o = tid - 64;
      float a0 = aggL[64 + o * 3 + 0];
      float a1 = aggL[64 + o * 3 + 1];
      float a2 = aggL[64 + o * 3 + 2];
      rv = sqrtf((a0 * a0 + a1 * a1 + a2 * a2) * (1.0f / 3.0f) + 1e-8f);
    }
    inv_agg[bid * 96 + tid] = rv;
  }
}

// ---------------------------------------------------------------------------
// K4: MLP layer Y = act(X@W + b). 32-row tiles -> 64 blocks. K in {96,128}.
// ---------------------------------------------------------------------------
__global__ void __launch_bounds__(256) k_mlp(
    const float* __restrict__ X, const float* __restrict__ W,
    const float* __restrict__ bias, float* __restrict__ Y,
    int K, int act) {
  const int r0 = blockIdx.x * 32;
  const int tid = threadIdx.x;

  __shared__ float A[32][129];

  for (int idx = tid; idx < 32 * K; idx += 256) {
    int n = idx / K, k = idx - n * K;
    A[n][k] = X[(size_t)(r0 + n) * K + k];
  }
  __syncthreads();

  const int rowg = tid >> 4, colg = tid & 15;
  const int r2 = rowg * 2, c8 = colg * 8;

  float acc[2][8];
  #pragma unroll
  for (int i = 0; i < 2; ++i)
    #pragma unroll
    for (int jj = 0; jj < 8; ++jj) acc[i][jj] = 0.0f;

  const float* wptr = W + c8;
  #pragma unroll 4
  for (int k = 0; k < K; ++k) {
    float4 w0 = *(const float4*)(wptr + k * 128);
    float4 w1v = *(const float4*)(wptr + k * 128 + 4);
    float av0 = A[r2 + 0][k];
    float av1 = A[r2 + 1][k];
    float wv[8] = {w0.x, w0.y, w0.z, w0.w, w1v.x, w1v.y, w1v.z, w1v.w};
    #pragma unroll
    for (int jj = 0; jj < 8; ++jj) {
      acc[0][jj] = fmaf(av0, wv[jj], acc[0][jj]);
      acc[1][jj] = fmaf(av1, wv[jj], acc[1][jj]);
    }
  }

  #pragma unroll
  for (int jj = 0; jj < 8; ++jj) {
    float bb = bias[c8 + jj];
    #pragma unroll
    for (int i = 0; i < 2; ++i) {
      float v = acc[i][jj] + bb;
      if (act) v = silu_f(v);
      Y[(size_t)(r0 + r2 + i) * 128 + c8 + jj] = v;
    }
  }
}

// ---------------------------------------------------------------------------
extern "C" void kernel_launch(void* const* d_in, const int* in_sizes, int n_in,
                              void* d_out, int out_size, void* d_ws, size_t ws_size,
                              hipStream_t stream) {
  const float* hf    = (const float*)d_in[0];
  const int*   z     = (const int*)  d_in[1];
  const float* pos   = (const float*)d_in[2];
  const float* e_feat= (const float*)d_in[4];
  const float* z_emb = (const float*)d_in[5];
  const float* vwW0  = (const float*)d_in[6];
  const float* vwb0  = (const float*)d_in[7];
  const float* vwW1  = (const float*)d_in[8];
  const float* vwb1  = (const float*)d_in[9];
  const float* vwW2  = (const float*)d_in[10];
  const float* vwb2  = (const float*)d_in[11];
  const float* scW0  = (const float*)d_in[12];
  const float* scb0  = (const float*)d_in[13];
  const float* scW1  = (const float*)d_in[14];
  const float* scb1  = (const float*)d_in[15];
  const float* scW2  = (const float*)d_in[16];
  const float* scb2  = (const float*)d_in[17];
  const float* oW0   = (const float*)d_in[18];
  const float* ob0   = (const float*)d_in[19];
  const float* oW1   = (const float*)d_in[20];
  const float* ob1   = (const float*)d_in[21];
  const float* oW2   = (const float*)d_in[22];
  const float* ob2   = (const float*)d_in[23];
  float* out = (float*)d_out;

  float* ws = (float*)d_ws;
  unsigned short* W2fh = (unsigned short*)(ws);            // 589824 fl
  unsigned short* W2fl = (unsigned short*)(ws + 589824);   // 589824 fl
  unsigned short* hTh  = (unsigned short*)(ws + 1179648);  // 65536 fl
  unsigned short* hTl  = (unsigned short*)(ws + 1245184);  // 65536 fl
  float* Pn     = ws + 1310720;   // 131072
  float* Pa     = Pn + 131072;    // 2048
  float* Pe     = Pa + 2048;      // 16384
  float* xvu    = Pe + 16384;     // 32768
  float* y1cw   = xvu + 32768;    // 4096
  float* values = y1cw + 4096;    // 163840
  float* invagg = values + 163840;// 196608
  unsigned short* W1fh = (unsigned short*)(invagg + 196608);  // 8192 fl
  unsigned short* W1fl = (unsigned short*)(invagg + 196608 + 8192);
  // H1/H2 alias the W2f region (dead after k_tp)
  float* H1     = ws;             // 262144
  float* H2     = ws + 262144;    // 262144

  hipMemsetAsync(values, 0, 163840 * sizeof(float), stream);

  k_castw2<<<576, 256, 0, stream>>>(vwW2, W2fh, W2fl);
  k_castw1<<<8, 256, 0, stream>>>(scW1, W1fh, W1fl);
  k_prep<<<256, 128, 0, stream>>>(hf, z, pos, z_emb, vwW0, vwb0, vwW1, vwb1,
                                  scW0, hTh, hTl, Pn, Pa, xvu, y1cw);
  k_pe<<<128, 128, 0, stream>>>(e_feat, scW0, scb0, Pe);
  k_tp<<<1024, 256, 0, stream>>>(hTh, hTl, W2fh, W2fl, vwb2, hf, xvu,
                                 y1cw, values);
  k_gate_agg<<<2048, 256, 0, stream>>>(Pa, Pe, Pn, W1fh, W1fl, scb1, scW2, scb2,
                                       y1cw, values, invagg);
  k_mlp<<<64, 256, 0, stream>>>(invagg, oW0, ob0, H1, 96, 1);
  k_mlp<<<64, 256, 0, stream>>>(H1, oW1, ob1, H2, 128, 1);
  k_mlp<<<64, 256, 0, stream>>>(H2, oW2, ob2, out, 128, 0);
}

// Round 12
// 320.104 us; speedup vs baseline: 1.1662x; 1.1662x over previous
//
#include <hip/hip_runtime.h>
#include <hip/hip_bf16.h>
#include <math.h>

// Sizes: B=16, N=64, nE=128, H=128, LAT=128, NS=64, NV=32, INV=96, D_NODE=160
#define SQRT3F 1.7320508075688772f
#define ALPHAF 0.10206207261596577f  // 1/sqrt(96)
#define PIF 3.14159265358979323846f

typedef short v8s __attribute__((ext_vector_type(8)));
typedef float v4f __attribute__((ext_vector_type(4)));

__device__ __forceinline__ float silu_f(float x) {
  return x / (1.0f + __expf(-x));
}
__device__ __forceinline__ float sigmoid_f(float x) {
  return 1.0f / (1.0f + __expf(-x));
}
__device__ __forceinline__ unsigned short f2bf(float f) {
  unsigned int u = __float_as_uint(f);
  unsigned int r = (u + 0x7fffu + ((u >> 16) & 1u)) >> 16;
  return (unsigned short)r;
}
__device__ __forceinline__ float bf2f(unsigned short h) {
  return __uint_as_float(((unsigned int)h) << 16);
}

// ---------------------------------------------------------------------------
// K-1: cast W2 (128 x 9216 fp32) into MFMA B-FRAGMENT order, bf16 hi/lo.
// ---------------------------------------------------------------------------
__global__ void __launch_bounds__(256) k_castw2(
    const float* __restrict__ W2, unsigned short* __restrict__ W2fh,
    unsigned short* __restrict__ W2fl) {
  const int T = blockIdx.x;           // column tile of 16
  const int tid = threadIdx.x;
  __shared__ float Tl[128][17];

  for (int idx = tid; idx < 2048; idx += 256) {
    int k = idx >> 4, cc = idx & 15;
    Tl[k][cc] = W2[(size_t)k * 9216 + T * 16 + cc];
  }
  __syncthreads();

  const int ks = tid >> 6, lane = tid & 63;
  const int q = lane >> 4, cq = lane & 15;
  const int k0 = ks * 32 + q * 8;
  unsigned short hv[8], lv[8];
  #pragma unroll
  for (int j = 0; j < 8; ++j) {
    float wv = Tl[k0 + j][cq];
    unsigned short h = f2bf(wv);
    hv[j] = h;
    lv[j] = f2bf(wv - bf2f(h));
  }
  size_t base = ((size_t)(T * 4 + ks) * 64 + lane) * 8;
  *(uint4*)&W2fh[base] = *(uint4*)hv;
  *(uint4*)&W2fl[base] = *(uint4*)lv;
}

// ---------------------------------------------------------------------------
// K-2: pack sc_W1 (128x128) into MFMA B-fragment order, bf16 hi/lo.
// ---------------------------------------------------------------------------
__global__ void __launch_bounds__(256) k_castw1(
    const float* __restrict__ W1, unsigned short* __restrict__ W1fh,
    unsigned short* __restrict__ W1fl) {
  const int s = blockIdx.x * 256 + threadIdx.x;   // 0..2047
  const int lane = s & 63;
  const int t = (s >> 6) & 7;
  const int ks = s >> 9;
  const int kbase = ks * 32 + (lane >> 4) * 8;
  const int n = t * 16 + (lane & 15);
  unsigned short hv[8], lv[8];
  #pragma unroll
  for (int j = 0; j < 8; ++j) {
    float w = W1[(size_t)(kbase + j) * 128 + n];
    unsigned short h = f2bf(w);
    hv[j] = h;
    lv[j] = f2bf(w - bf2f(h));
  }
  *(uint4*)&W1fh[(size_t)s * 8] = *(uint4*)hv;
  *(uint4*)&W1fl[(size_t)s * 8] = *(uint4*)lv;
}

// ---------------------------------------------------------------------------
// K0 v3: per-node prep, 2 nodes per block. grid=512, block=128.
// (R11: 256 blocks = 1 block/CU = 2 waves -> latency-bound; now 2 blocks/CU.)
// ---------------------------------------------------------------------------
__global__ void k_prep(const float* __restrict__ hf, const int* __restrict__ z,
                       const float* __restrict__ pos, const float* __restrict__ z_emb,
                       const float* __restrict__ vwW0, const float* __restrict__ vwb0,
                       const float* __restrict__ vwW1, const float* __restrict__ vwb1,
                       const float* __restrict__ scW0,
                       unsigned short* __restrict__ hTh, unsigned short* __restrict__ hTl,
                       float* __restrict__ Pn, float* __restrict__ Pa,
                       float* __restrict__ xvu, float* __restrict__ y1cw) {
  const int g0 = blockIdx.x * 2;
  const int b = g0 >> 6;
  const int t = threadIdx.x;

  __shared__ float vin[2][64];
  __shared__ float invn[2][96];
  __shared__ float h0[2][128];
  __shared__ float uS[2][3];
  __shared__ float rS[2];

  if (t < 2) {
    const int g = g0 + t;
    float px = pos[g * 3 + 0] - pos[(b * 64) * 3 + 0];
    float py = pos[g * 3 + 1] - pos[(b * 64) * 3 + 1];
    float pz = pos[g * 3 + 2] - pos[(b * 64) * 3 + 2];
    float r = sqrtf(px * px + py * py + pz * pz + 1e-12f);
    float rm = fmaxf(r, 1e-8f);
    uS[t][0] = px / rm; uS[t][1] = py / rm; uS[t][2] = pz / rm;
    rS[t] = r;
  }
  __syncthreads();

  if (t < 32) {
    const float delta = 6.0f / 31.0f;
    const float gamma = 1.0f / (delta * delta + 1e-12f);
    #pragma unroll
    for (int nn = 0; nn < 2; ++nn) {
      int zi = z[g0 + nn];
      vin[nn][t] = z_emb[zi * 32 + t];
      float rc = fminf(rS[nn], 6.0f);
      float d = rc - (float)t * delta;
      vin[nn][32 + t] = __expf(-gamma * d * d);
      float a = hf[(g0 + nn) * 160 + 64 + t * 3 + 0] * uS[nn][0]
              + hf[(g0 + nn) * 160 + 64 + t * 3 + 1] * uS[nn][1]
              + hf[(g0 + nn) * 160 + 64 + t * 3 + 2] * uS[nn][2];
      xvu[(g0 + nn) * 32 + t] = a;
    }
  }
  if (t < 96) {
    #pragma unroll
    for (int nn = 0; nn < 2; ++nn) {
      const int g = g0 + nn;
      if (t < 64) {
        invn[nn][t] = hf[g * 160 + t];
      } else {
        int o = t - 64;
        float v0 = hf[g * 160 + 64 + o * 3 + 0];
        float v1 = hf[g * 160 + 64 + o * 3 + 1];
        float v2 = hf[g * 160 + 64 + o * 3 + 2];
        invn[nn][t] = sqrtf((v0 * v0 + v1 * v1 + v2 * v2) * (1.0f / 3.0f) + 1e-8f);
      }
    }
  }
  if (t < 2) {
    const int n = (g0 + t) & 63;
    float r = rS[t];
    float cw = 0.0f;
    if (r <= 6.0f && n != 0) cw = 0.5f * (cosf(PIF * r * (1.0f / 6.0f)) + 1.0f);
    y1cw[(g0 + t) * 4 + 0] = SQRT3F * uS[t][0];
    y1cw[(g0 + t) * 4 + 1] = SQRT3F * uS[t][1];
    y1cw[(g0 + t) * 4 + 2] = SQRT3F * uS[t][2];
    y1cw[(g0 + t) * 4 + 3] = cw;
  }
  __syncthreads();

  {
    float a0 = vwb0[t], a1 = a0;
    #pragma unroll 8
    for (int k = 0; k < 64; ++k) {
      float w = vwW0[k * 128 + t];
      a0 = fmaf(vin[0][k], w, a0);
      a1 = fmaf(vin[1][k], w, a1);
    }
    h0[0][t] = silu_f(a0); h0[1][t] = silu_f(a1);
  }
  __syncthreads();
  {
    float a0 = vwb1[t], a1 = a0;
    #pragma unroll 8
    for (int k = 0; k < 128; ++k) {
      float w = vwW1[k * 128 + t];
      a0 = fmaf(h0[0][k], w, a0);
      a1 = fmaf(h0[1][k], w, a1);
    }
    float hv[2] = {silu_f(a0), silu_f(a1)};
    #pragma unroll
    for (int nn = 0; nn < 2; ++nn) {
      unsigned short hh = f2bf(hv[nn]);
      hTh[(size_t)(g0 + nn) * 128 + t] = hh;
      hTl[(size_t)(g0 + nn) * 128 + t] = f2bf(hv[nn] - bf2f(hh));
    }
  }
  {
    float p0 = 0.f, p1 = 0.f;
    #pragma unroll 8
    for (int k = 0; k < 96; ++k) {
      float w = scW0[(96 + k) * 128 + t];
      p0 = fmaf(invn[0][k], w, p0);
      p1 = fmaf(invn[1][k], w, p1);
    }
    #pragma unroll 8
    for (int k = 0; k < 64; ++k) {
      float w = scW0[(192 + k) * 128 + t];
      p0 = fmaf(vin[0][k], w, p0);
      p1 = fmaf(vin[1][k], w, p1);
    }
    Pn[(g0 + 0) * 128 + t] = p0;
    Pn[(g0 + 1) * 128 + t] = p1;
  }
  if ((g0 & 63) == 0) {
    float p = 0.0f;
    #pragma unroll 8
    for (int k = 0; k < 96; ++k) p = fmaf(invn[0][k], scW0[k * 128 + t], p);
    Pa[b * 128 + t] = p;
  }
}

// ---------------------------------------------------------------------------
// KPe: Pe[e][t] = sc_b0[t] + e_feat[e]@We. grid=128, block=128.
// ---------------------------------------------------------------------------
__global__ void k_pe(const float* __restrict__ e_feat, const float* __restrict__ scW0,
                     const float* __restrict__ scb0, float* __restrict__ Pe) {
  const int e = blockIdx.x;
  const int t = threadIdx.x;
  float a = scb0[t];
  #pragma unroll
  for (int k = 0; k < 16; ++k) a = fmaf(e_feat[e * 16 + k], scW0[(256 + k) * 128 + t], a);
  Pe[e * 128 + t] = a;
}

// ---------------------------------------------------------------------------
// K2 v12: MFMA GEMM + register contraction, canonical LDS-B pipeline.
// R10/R11 lesson: B-through-VGPR prefetch was register-starved (VGPR 52-80)
// -> serialized L2-latency loads. Now: 64-node M-tile, all 4 waves SHARE each
// B tile staged in LDS (double-buffered, reg roundtrip); A-frags in regs.
// grid = 512: cs = bid&31 (col split, XCD-pinned via cs&7), g0=(bid>>5)*64.
// Per block 18 tiles; racc all segments live (compile-time indices only).
// LDS combine atomic-free (waves own disjoint node rows); global flush to 8
// per-XCD partial copies (XCD-local atomics), summed by k_reduce.
// ---------------------------------------------------------------------------
__device__ __forceinline__ int tile_of(int cs, int t) {
  if (t < 8)  return cs * 8 + t;               // w1: 0..255
  if (t < 12) return 256 + cs * 4 + (t - 8);   // w2: 256..383
  if (t < 14) return 384 + cs * 2 + (t - 12);  // w3: 384..447
  return 448 + cs * 4 + (t - 14);              // w4: 448..575
}

__global__ void __launch_bounds__(256) k_tp(
    const unsigned short* __restrict__ hTh, const unsigned short* __restrict__ hTl,
    const unsigned short* __restrict__ W2fh, const unsigned short* __restrict__ W2fl,
    const float* __restrict__ b2, const float* __restrict__ hf,
    const float* __restrict__ xvu, const float* __restrict__ y1cw,
    float* __restrict__ values8) {
  const int bid = blockIdx.x;
  const int cs = bid & 31;
  const int g0 = (bid >> 5) * 64;
  const int p8 = cs & 7;
  const int tid = threadIdx.x;
  const int w = tid >> 6, l = tid & 63;
  const int q = l >> 4, cq = l & 15;

  __shared__ unsigned short BstH[2][256][8];   // [buf][ks*64+l][8]
  __shared__ unsigned short BstL[2][256][8];
  __shared__ float valsS[64][160];
  __shared__ float svS[64][32];

  for (int idx = tid; idx < 64 * 160; idx += 256) ((float*)valsS)[idx] = 0.f;
  for (int idx = tid; idx < 64 * 32; idx += 256) ((float*)svS)[idx] = 0.f;

  // A fragments: wave w owns nodes g0+w*16 .. +16 (m=cq, k=ks*32+q*8+j)
  const int anode = g0 + w * 16 + cq;
  v8s ah0 = *(const v8s*)&hTh[(size_t)anode * 128 + 0 * 32 + q * 8];
  v8s ah1 = *(const v8s*)&hTh[(size_t)anode * 128 + 1 * 32 + q * 8];
  v8s ah2 = *(const v8s*)&hTh[(size_t)anode * 128 + 2 * 32 + q * 8];
  v8s ah3 = *(const v8s*)&hTh[(size_t)anode * 128 + 3 * 32 + q * 8];
  v8s al0 = *(const v8s*)&hTl[(size_t)anode * 128 + 0 * 32 + q * 8];
  v8s al1 = *(const v8s*)&hTl[(size_t)anode * 128 + 1 * 32 + q * 8];
  v8s al2 = *(const v8s*)&hTl[(size_t)anode * 128 + 2 * 32 + q * 8];
  v8s al3 = *(const v8s*)&hTl[(size_t)anode * 128 + 3 * 32 + q * 8];

  // segment accumulators (all compile-time indexed)
  float racc1[4][4] = {{0.f}};
  float racc2[2][4] = {{0.f}};
  float racc3[2][4][3] = {{{0.f}}};
  float racc4[4][4] = {{0.f}};

  const int nrow = w * 16 + q * 4;    // node base for this lane's D rows

  // stage tile 0
  {
    const int T = tile_of(cs, 0);
    uint4 gh = *(const uint4*)&W2fh[(size_t)T * 2048 + tid * 8];
    uint4 gl = *(const uint4*)&W2fl[(size_t)T * 2048 + tid * 8];
    *(uint4*)&BstH[0][tid][0] = gh;
    *(uint4*)&BstL[0][tid][0] = gl;
  }
  __syncthreads();

  #pragma unroll
  for (int t = 0; t < 18; ++t) {
    const int buf = t & 1;
    uint4 gh, gl;
    if (t < 17) {
      const int Tn = tile_of(cs, t + 1);
      gh = *(const uint4*)&W2fh[(size_t)Tn * 2048 + tid * 8];
      gl = *(const uint4*)&W2fl[(size_t)Tn * 2048 + tid * 8];
    }

    const int T = tile_of(cs, t);
    v8s bh0 = *(const v8s*)&BstH[buf][0 * 64 + l][0];
    v8s bh1 = *(const v8s*)&BstH[buf][1 * 64 + l][0];
    v8s bh2 = *(const v8s*)&BstH[buf][2 * 64 + l][0];
    v8s bh3 = *(const v8s*)&BstH[buf][3 * 64 + l][0];
    v8s bl0 = *(const v8s*)&BstL[buf][0 * 64 + l][0];
    v8s bl1 = *(const v8s*)&BstL[buf][1 * 64 + l][0];
    v8s bl2 = *(const v8s*)&BstL[buf][2 * 64 + l][0];
    v8s bl3 = *(const v8s*)&BstL[buf][3 * 64 + l][0];

    v4f a0 = (v4f){0.f, 0.f, 0.f, 0.f};
    v4f a1 = (v4f){0.f, 0.f, 0.f, 0.f};
    v4f a2 = (v4f){0.f, 0.f, 0.f, 0.f};
    a0 = __builtin_amdgcn_mfma_f32_16x16x32_bf16(ah0, bh0, a0, 0, 0, 0);
    a1 = __builtin_amdgcn_mfma_f32_16x16x32_bf16(al0, bh0, a1, 0, 0, 0);
    a2 = __builtin_amdgcn_mfma_f32_16x16x32_bf16(ah0, bl0, a2, 0, 0, 0);
    a0 = __builtin_amdgcn_mfma_f32_16x16x32_bf16(ah1, bh1, a0, 0, 0, 0);
    a1 = __builtin_amdgcn_mfma_f32_16x16x32_bf16(al1, bh1, a1, 0, 0, 0);
    a2 = __builtin_amdgcn_mfma_f32_16x16x32_bf16(ah1, bl1, a2, 0, 0, 0);
    a0 = __builtin_amdgcn_mfma_f32_16x16x32_bf16(ah2, bh2, a0, 0, 0, 0);
    a1 = __builtin_amdgcn_mfma_f32_16x16x32_bf16(al2, bh2, a1, 0, 0, 0);
    a2 = __builtin_amdgcn_mfma_f32_16x16x32_bf16(ah2, bl2, a2, 0, 0, 0);
    a0 = __builtin_amdgcn_mfma_f32_16x16x32_bf16(ah3, bh3, a0, 0, 0, 0);
    a1 = __builtin_amdgcn_mfma_f32_16x16x32_bf16(al3, bh3, a1, 0, 0, 0);
    a2 = __builtin_amdgcn_mfma_f32_16x16x32_bf16(ah3, bl3, a2, 0, 0, 0);
    a0 += a1; a0 += a2;
    const float bj = b2[T * 16 + cq];
    v4f tp = a0;
    tp[0] += bj; tp[1] += bj; tp[2] += bj; tp[3] += bj;

    // contraction accumulate (inputs: broadcast global loads, L1/L2-hot)
    if (t < 8) {                        // w1: i = cs*2 + (t>>2), m = t&3
      const int i = cs * 2 + (t >> 2);
      const int m = t & 3;
      #pragma unroll
      for (int r = 0; r < 4; ++r)
        racc1[m][r] = fmaf(hf[(size_t)(g0 + nrow + r) * 160 + i], tp[r], racc1[m][r]);
    } else if (t < 12) {                // w2: i = cs*2 + ((t-8)>>1), m = (t-8)&1
      const int i = cs * 2 + ((t - 8) >> 1);
      const int m = (t - 8) & 1;
      #pragma unroll
      for (int r = 0; r < 4; ++r)
        racc2[m][r] = fmaf(hf[(size_t)(g0 + nrow + r) * 160 + i], tp[r], racc2[m][r]);
    } else if (t < 14) {                // w3: i = cs, m = (t-12)&1
      const int m = (t - 12) & 1;
      #pragma unroll
      for (int r = 0; r < 4; ++r) {
        const float* xvp = hf + (size_t)(g0 + nrow + r) * 160 + 64 + 3 * cs;
        #pragma unroll
        for (int cc = 0; cc < 3; ++cc)
          racc3[m][r][cc] = fmaf(xvp[cc], tp[r], racc3[m][r][cc]);
      }
    } else {                            // w4: i = cs, m = (t-14)&3
      const int m = (t - 14) & 3;
      #pragma unroll
      for (int r = 0; r < 4; ++r)
        racc4[m][r] = fmaf(xvu[(size_t)(g0 + nrow + r) * 32 + cs], tp[r], racc4[m][r]);
    }

    if (t < 17) {
      const int nbuf = buf ^ 1;
      *(uint4*)&BstH[nbuf][tid][0] = gh;
      *(uint4*)&BstL[nbuf][tid][0] = gl;
    }
    __syncthreads();
  }

  // write racc into LDS (owner-exclusive, no atomics)
  #pragma unroll
  for (int r = 0; r < 4; ++r) {
    const int n = nrow + r;
    #pragma unroll
    for (int m = 0; m < 4; ++m)
      valsS[n][m * 16 + cq] += racc1[m][r] + racc4[m][r];
    #pragma unroll
    for (int m = 0; m < 2; ++m)
      svS[n][m * 16 + cq] += racc2[m][r];
    #pragma unroll
    for (int m = 0; m < 2; ++m)
      #pragma unroll
      for (int cc = 0; cc < 3; ++cc)
        valsS[n][64 + 3 * (m * 16 + cq) + cc] += racc3[m][r][cc];
  }
  __syncthreads();

  // flush to this XCD's partial copy (4 colliding blocks, all same XCD)
  float* vtgt = values8 + (size_t)p8 * 163840;
  const float* y1b = y1cw + (size_t)g0 * 4;
  for (int idx = tid; idx < 10240; idx += 256) {
    int n = idx / 160, d = idx - n * 160;
    float v = valsS[n][d];
    if (d >= 64) {
      int dd = d - 64, o = dd / 3, cc = dd - 3 * o;
      v = fmaf(svS[n][o], y1b[n * 4 + cc], v);
    }
    atomicAdd(&vtgt[(size_t)(g0 + n) * 160 + d], v);
  }
}

// ---------------------------------------------------------------------------
// K2b: values[n][d] = ALPHAF * sum_p values8[p][n][d]. grid=160, block=256,
// one float4 per thread (163840/4 = 40960 slots).
// ---------------------------------------------------------------------------
__global__ void __launch_bounds__(256) k_reduce(
    const float* __restrict__ values8, float* __restrict__ values) {
  const int s = blockIdx.x * 256 + threadIdx.x;   // 0..40959
  float4 acc = make_float4(0.f, 0.f, 0.f, 0.f);
  #pragma unroll
  for (int p = 0; p < 8; ++p) {
    float4 v = *(const float4*)&values8[(size_t)p * 163840 + s * 4];
    acc.x += v.x; acc.y += v.y; acc.z += v.z; acc.w += v.w;
  }
  acc.x *= ALPHAF; acc.y *= ALPHAF; acc.z *= ALPHAF; acc.w *= ALPHAF;
  *(float4*)&values[(size_t)s * 4] = acc;
}

// ---------------------------------------------------------------------------
// K3 v4: MFMA gate MLP + aggregation per (b,e). grid=2048, block=256.
// ---------------------------------------------------------------------------
__global__ void __launch_bounds__(256, 4) k_gate_agg(
    const float* __restrict__ Pa, const float* __restrict__ Pe,
    const float* __restrict__ Pn,
    const unsigned short* __restrict__ W1fh, const unsigned short* __restrict__ W1fl,
    const float* __restrict__ b1, const float* __restrict__ W2v,
    const float* __restrict__ b2s, const float* __restrict__ y1cw,
    const float* __restrict__ values, float* __restrict__ inv_agg) {
  const int bid = blockIdx.x;
  const int b = bid >> 7, e = bid & 127;
  const int tid = threadIdx.x;

  __shared__ float Prow[128];
  __shared__ float gpre[64];
  __shared__ float gateL[64];
  __shared__ float aggL[160];
  __shared__ float normS;

  if (tid < 128) Prow[tid] = Pa[b * 128 + tid] + Pe[e * 128 + tid];
  __syncthreads();

  const int w = tid >> 6, l = tid & 63;
  const int q = l >> 4, cq = l & 15;
  const int node = w * 16 + cq;
  const float* pnrow = Pn + (size_t)(b * 64 + node) * 128;

  v4f acc[8];
  #pragma unroll
  for (int t = 0; t < 8; ++t) acc[t] = (v4f){0.f, 0.f, 0.f, 0.f};

  #pragma unroll
  for (int ks = 0; ks < 4; ++ks) {
    const int k0 = ks * 32 + q * 8;
    float4 p0 = *(const float4*)(pnrow + k0);
    float4 p1 = *(const float4*)(pnrow + k0 + 4);
    float4 r0 = *(const float4*)(&Prow[k0]);
    float4 r1 = *(const float4*)(&Prow[k0 + 4]);
    float xv[8] = {p0.x + r0.x, p0.y + r0.y, p0.z + r0.z, p0.w + r0.w,
                   p1.x + r1.x, p1.y + r1.y, p1.z + r1.z, p1.w + r1.w};
    v8s avh, avl;
    #pragma unroll
    for (int j = 0; j < 8; ++j) {
      float x = silu_f(xv[j]);
      unsigned short h = f2bf(x);
      avh[j] = (short)h;
      avl[j] = (short)f2bf(x - bf2f(h));
    }
    #pragma unroll
    for (int t = 0; t < 8; ++t) {
      const size_t fb = (size_t)((ks * 8 + t) * 64 + l) * 8;
      v8s bh = *(const v8s*)&W1fh[fb];
      v8s bl = *(const v8s*)&W1fl[fb];
      acc[t] = __builtin_amdgcn_mfma_f32_16x16x32_bf16(avh, bh, acc[t], 0, 0, 0);
      acc[t] = __builtin_amdgcn_mfma_f32_16x16x32_bf16(avl, bh, acc[t], 0, 0, 0);
      acc[t] = __builtin_amdgcn_mfma_f32_16x16x32_bf16(avh, bl, acc[t], 0, 0, 0);
    }
  }

  float part0 = 0.f, part1 = 0.f, part2 = 0.f, part3 = 0.f;
  #pragma unroll
  for (int t = 0; t < 8; ++t) {
    float bb = b1[t * 16 + cq];
    float wg = W2v[t * 16 + cq];
    part0 = fmaf(silu_f(acc[t][0] + bb), wg, part0);
    part1 = fmaf(silu_f(acc[t][1] + bb), wg, part1);
    part2 = fmaf(silu_f(acc[t][2] + bb), wg, part2);
    part3 = fmaf(silu_f(acc[t][3] + bb), wg, part3);
  }
  #pragma unroll
  for (int off = 1; off < 16; off <<= 1) {
    part0 += __shfl_xor(part0, off);
    part1 += __shfl_xor(part1, off);
    part2 += __shfl_xor(part2, off);
    part3 += __shfl_xor(part3, off);
  }
  if (cq == 0) {
    gpre[w * 16 + q * 4 + 0] = part0;
    gpre[w * 16 + q * 4 + 1] = part1;
    gpre[w * 16 + q * 4 + 2] = part2;
    gpre[w * 16 + q * 4 + 3] = part3;
  }
  __syncthreads();

  if (tid < 64) {
    float gv = sigmoid_f(gpre[tid] + b2s[0]);
    gv *= y1cw[(b * 64 + tid) * 4 + 3];
    gateL[tid] = gv;
    float t2 = gv;
    #pragma unroll
    for (int off = 32; off > 0; off >>= 1) t2 += __shfl_down(t2, off);
    if (tid == 0) normS = fmaxf(t2, 1e-8f);
  }
  __syncthreads();

  if (tid < 160) {
    float a = 0.0f;
    const float* vp = values + (size_t)b * 64 * 160 + tid;
    #pragma unroll 4
    for (int n = 0; n < 64; ++n) a = fmaf(gateL[n], vp[n * 160], a);
    aggL[tid] = a / normS;
  }
  __syncthreads();
  if (tid < 96) {
    float rv;
    if (tid < 64) {
      rv = aggL[tid];
    } else {
      int o = tid - 64;
      float a0 = aggL[64 + o * 3 + 0];
      float a1 = aggL[64 + o * 3 + 1];
      float a2 = aggL[64 + o * 3 + 2];
      rv = sqrtf((a0 * a0 + a1 * a1 + a2 * a2) * (1.0f / 3.0f) + 1e-8f);
    }
    inv_agg[bid * 96 + tid] = rv;
  }
}

// ---------------------------------------------------------------------------
// K4: MLP layer Y = act(X@W + b). 32-row tiles -> 64 blocks. K in {96,128}.
// ---------------------------------------------------------------------------
__global__ void __launch_bounds__(256) k_mlp(
    const float* __restrict__ X, const float* __restrict__ W,
    const float* __restrict__ bias, float* __restrict__ Y,
    int K, int act) {
  const int r0 = blockIdx.x * 32;
  const int tid = threadIdx.x;

  __shared__ float A[32][129];

  for (int idx = tid; idx < 32 * K; idx += 256) {
    int n = idx / K, k = idx - n * K;
    A[n][k] = X[(size_t)(r0 + n) * K + k];
  }
  __syncthreads();

  const int rowg = tid >> 4, colg = tid & 15;
  const int r2 = rowg * 2, c8 = colg * 8;

  float acc[2][8];
  #pragma unroll
  for (int i = 0; i < 2; ++i)
    #pragma unroll
    for (int jj = 0; jj < 8; ++jj) acc[i][jj] = 0.0f;

  const float* wptr = W + c8;
  #pragma unroll 4
  for (int k = 0; k < K; ++k) {
    float4 w0 = *(const float4*)(wptr + k * 128);
    float4 w1v = *(const float4*)(wptr + k * 128 + 4);
    float av0 = A[r2 + 0][k];
    float av1 = A[r2 + 1][k];
    float wv[8] = {w0.x, w0.y, w0.z, w0.w, w1v.x, w1v.y, w1v.z, w1v.w};
    #pragma unroll
    for (int jj = 0; jj < 8; ++jj) {
      acc[0][jj] = fmaf(av0, wv[jj], acc[0][jj]);
      acc[1][jj] = fmaf(av1, wv[jj], acc[1][jj]);
    }
  }

  #pragma unroll
  for (int jj = 0; jj < 8; ++jj) {
    float bb = bias[c8 + jj];
    #pragma unroll
    for (int i = 0; i < 2; ++i) {
      float v = acc[i][jj] + bb;
      if (act) v = silu_f(v);
      Y[(size_t)(r0 + r2 + i) * 128 + c8 + jj] = v;
    }
  }
}

// ---------------------------------------------------------------------------
extern "C" void kernel_launch(void* const* d_in, const int* in_sizes, int n_in,
                              void* d_out, int out_size, void* d_ws, size_t ws_size,
                              hipStream_t stream) {
  const float* hf    = (const float*)d_in[0];
  const int*   z     = (const int*)  d_in[1];
  const float* pos   = (const float*)d_in[2];
  const float* e_feat= (const float*)d_in[4];
  const float* z_emb = (const float*)d_in[5];
  const float* vwW0  = (const float*)d_in[6];
  const float* vwb0  = (const float*)d_in[7];
  const float* vwW1  = (const float*)d_in[8];
  const float* vwb1  = (const float*)d_in[9];
  const float* vwW2  = (const float*)d_in[10];
  const float* vwb2  = (const float*)d_in[11];
  const float* scW0  = (const float*)d_in[12];
  const float* scb0  = (const float*)d_in[13];
  const float* scW1  = (const float*)d_in[14];
  const float* scb1  = (const float*)d_in[15];
  const float* scW2  = (const float*)d_in[16];
  const float* scb2  = (const float*)d_in[17];
  const float* oW0   = (const float*)d_in[18];
  const float* ob0   = (const float*)d_in[19];
  const float* oW1   = (const float*)d_in[20];
  const float* ob1   = (const float*)d_in[21];
  const float* oW2   = (const float*)d_in[22];
  const float* ob2   = (const float*)d_in[23];
  float* out = (float*)d_out;

  float* ws = (float*)d_ws;
  unsigned short* W2fh = (unsigned short*)(ws);            // 589824 fl
  unsigned short* W2fl = (unsigned short*)(ws + 589824);   // 589824 fl
  unsigned short* hTh  = (unsigned short*)(ws + 1179648);  // 65536 fl
  unsigned short* hTl  = (unsigned short*)(ws + 1245184);  // 65536 fl
  float* Pn     = ws + 1310720;   // 131072
  float* Pa     = Pn + 131072;    // 2048
  float* Pe     = Pa + 2048;      // 16384
  float* xvu    = Pe + 16384;     // 32768
  float* y1cw   = xvu + 32768;    // 4096
  float* values = y1cw + 4096;    // 163840
  float* invagg = values + 163840;// 196608
  unsigned short* W1fh = (unsigned short*)(invagg + 196608);  // 8192 fl
  unsigned short* W1fl = (unsigned short*)(invagg + 196608 + 8192);
  float* values8 = invagg + 196608 + 16384;  // 8*163840 = 1310720 fl
  // H1/H2 alias the W2f region (dead after k_tp)
  float* H1     = ws;             // 262144
  float* H2     = ws + 262144;    // 262144

  hipMemsetAsync(values8, 0, 8 * 163840 * sizeof(float), stream);

  k_castw2<<<576, 256, 0, stream>>>(vwW2, W2fh, W2fl);
  k_castw1<<<8, 256, 0, stream>>>(scW1, W1fh, W1fl);
  k_prep<<<512, 128, 0, stream>>>(hf, z, pos, z_emb, vwW0, vwb0, vwW1, vwb1,
                                  scW0, hTh, hTl, Pn, Pa, xvu, y1cw);
  k_pe<<<128, 128, 0, stream>>>(e_feat, scW0, scb0, Pe);
  k_tp<<<512, 256, 0, stream>>>(hTh, hTl, W2fh, W2fl, vwb2, hf, xvu,
                                y1cw, values8);
  k_reduce<<<160, 256, 0, stream>>>(values8, values);
  k_gate_agg<<<2048, 256, 0, stream>>>(Pa, Pe, Pn, W1fh, W1fl, scb1, scW2, scb2,
                                       y1cw, values, invagg);
  k_mlp<<<64, 256, 0, stream>>>(invagg, oW0, ob0, H1, 96, 1);
  k_mlp<<<64, 256, 0, stream>>>(H1, oW1, ob1, H2, 128, 1);
  k_mlp<<<64, 256, 0, stream>>>(H2, oW2, ob2, out, 128, 0);
}

// Round 13
// 224.097 us; speedup vs baseline: 1.6659x; 1.4284x over previous
//
#include <hip/hip_runtime.h>
#include <hip/hip_bf16.h>
#include <math.h>

// Sizes: B=16, N=64, nE=128, H=128, LAT=128, NS=64, NV=32, INV=96, D_NODE=160
#define SQRT3F 1.7320508075688772f
#define ALPHAF 0.10206207261596577f  // 1/sqrt(96)
#define PIF 3.14159265358979323846f

typedef short v8s __attribute__((ext_vector_type(8)));
typedef float v4f __attribute__((ext_vector_type(4)));

__device__ __forceinline__ float silu_f(float x) {
  return x / (1.0f + __expf(-x));
}
__device__ __forceinline__ float sigmoid_f(float x) {
  return 1.0f / (1.0f + __expf(-x));
}
__device__ __forceinline__ unsigned short f2bf(float f) {
  unsigned int u = __float_as_uint(f);
  unsigned int r = (u + 0x7fffu + ((u >> 16) & 1u)) >> 16;
  return (unsigned short)r;
}
__device__ __forceinline__ float bf2f(unsigned short h) {
  return __uint_as_float(((unsigned int)h) << 16);
}

// ---------------------------------------------------------------------------
// K-1: cast W2 (128 x 9216 fp32) into MFMA B-FRAGMENT order, bf16 hi/lo.
// ---------------------------------------------------------------------------
__global__ void __launch_bounds__(256) k_castw2(
    const float* __restrict__ W2, unsigned short* __restrict__ W2fh,
    unsigned short* __restrict__ W2fl) {
  const int T = blockIdx.x;           // column tile of 16
  const int tid = threadIdx.x;
  __shared__ float Tl[128][17];

  for (int idx = tid; idx < 2048; idx += 256) {
    int k = idx >> 4, cc = idx & 15;
    Tl[k][cc] = W2[(size_t)k * 9216 + T * 16 + cc];
  }
  __syncthreads();

  const int ks = tid >> 6, lane = tid & 63;
  const int q = lane >> 4, cq = lane & 15;
  const int k0 = ks * 32 + q * 8;
  unsigned short hv[8], lv[8];
  #pragma unroll
  for (int j = 0; j < 8; ++j) {
    float wv = Tl[k0 + j][cq];
    unsigned short h = f2bf(wv);
    hv[j] = h;
    lv[j] = f2bf(wv - bf2f(h));
  }
  size_t base = ((size_t)(T * 4 + ks) * 64 + lane) * 8;
  *(uint4*)&W2fh[base] = *(uint4*)hv;
  *(uint4*)&W2fl[base] = *(uint4*)lv;
}

// ---------------------------------------------------------------------------
// K-2: pack sc_W1 (128x128) into MFMA B-fragment order, bf16 hi/lo.
// ---------------------------------------------------------------------------
__global__ void __launch_bounds__(256) k_castw1(
    const float* __restrict__ W1, unsigned short* __restrict__ W1fh,
    unsigned short* __restrict__ W1fl) {
  const int s = blockIdx.x * 256 + threadIdx.x;   // 0..2047
  const int lane = s & 63;
  const int t = (s >> 6) & 7;
  const int ks = s >> 9;
  const int kbase = ks * 32 + (lane >> 4) * 8;
  const int n = t * 16 + (lane & 15);
  unsigned short hv[8], lv[8];
  #pragma unroll
  for (int j = 0; j < 8; ++j) {
    float w = W1[(size_t)(kbase + j) * 128 + n];
    unsigned short h = f2bf(w);
    hv[j] = h;
    lv[j] = f2bf(w - bf2f(h));
  }
  *(uint4*)&W1fh[(size_t)s * 8] = *(uint4*)hv;
  *(uint4*)&W1fl[(size_t)s * 8] = *(uint4*)lv;
}

// ---------------------------------------------------------------------------
// K-3: pack the out-MLP weights (oW0 96x128, oW1 128x128, oW2 128x128) into
// B-fragment bf16 hi/lo. 5632 slots, grid=22. Runs AFTER k_tp, writes into
// the dead W2f region (no extra ws).
// ---------------------------------------------------------------------------
__global__ void __launch_bounds__(256) k_packout(
    const float* __restrict__ W0, const float* __restrict__ W1,
    const float* __restrict__ W2,
    unsigned short* __restrict__ O0h, unsigned short* __restrict__ O0l,
    unsigned short* __restrict__ O1h, unsigned short* __restrict__ O1l,
    unsigned short* __restrict__ O2h, unsigned short* __restrict__ O2l) {
  const int s = blockIdx.x * 256 + threadIdx.x;   // 0..5631
  if (s >= 5632) return;
  const float* W; unsigned short *fh, *fl; int s0;
  if (s < 1536)      { W = W0; fh = O0h; fl = O0l; s0 = s; }
  else if (s < 3584) { W = W1; fh = O1h; fl = O1l; s0 = s - 1536; }
  else               { W = W2; fh = O2h; fl = O2l; s0 = s - 3584; }
  const int lane = s0 & 63;
  const int t = (s0 >> 6) & 7;
  const int ks = s0 >> 9;
  const int kbase = ks * 32 + (lane >> 4) * 8;
  const int n = t * 16 + (lane & 15);
  unsigned short hv[8], lv[8];
  #pragma unroll
  for (int j = 0; j < 8; ++j) {
    float w = W[(size_t)(kbase + j) * 128 + n];
    unsigned short h = f2bf(w);
    hv[j] = h;
    lv[j] = f2bf(w - bf2f(h));
  }
  *(uint4*)&fh[(size_t)s0 * 8] = *(uint4*)hv;
  *(uint4*)&fl[(size_t)s0 * 8] = *(uint4*)lv;
}

// ---------------------------------------------------------------------------
// K0 v3: per-node prep, 2 nodes per block. grid=512, block=128.
// ---------------------------------------------------------------------------
__global__ void k_prep(const float* __restrict__ hf, const int* __restrict__ z,
                       const float* __restrict__ pos, const float* __restrict__ z_emb,
                       const float* __restrict__ vwW0, const float* __restrict__ vwb0,
                       const float* __restrict__ vwW1, const float* __restrict__ vwb1,
                       const float* __restrict__ scW0,
                       unsigned short* __restrict__ hTh, unsigned short* __restrict__ hTl,
                       float* __restrict__ Pn, float* __restrict__ Pa,
                       float* __restrict__ xvu, float* __restrict__ y1cw) {
  const int g0 = blockIdx.x * 2;
  const int b = g0 >> 6;
  const int t = threadIdx.x;

  __shared__ float vin[2][64];
  __shared__ float invn[2][96];
  __shared__ float h0[2][128];
  __shared__ float uS[2][3];
  __shared__ float rS[2];

  if (t < 2) {
    const int g = g0 + t;
    float px = pos[g * 3 + 0] - pos[(b * 64) * 3 + 0];
    float py = pos[g * 3 + 1] - pos[(b * 64) * 3 + 1];
    float pz = pos[g * 3 + 2] - pos[(b * 64) * 3 + 2];
    float r = sqrtf(px * px + py * py + pz * pz + 1e-12f);
    float rm = fmaxf(r, 1e-8f);
    uS[t][0] = px / rm; uS[t][1] = py / rm; uS[t][2] = pz / rm;
    rS[t] = r;
  }
  __syncthreads();

  if (t < 32) {
    const float delta = 6.0f / 31.0f;
    const float gamma = 1.0f / (delta * delta + 1e-12f);
    #pragma unroll
    for (int nn = 0; nn < 2; ++nn) {
      int zi = z[g0 + nn];
      vin[nn][t] = z_emb[zi * 32 + t];
      float rc = fminf(rS[nn], 6.0f);
      float d = rc - (float)t * delta;
      vin[nn][32 + t] = __expf(-gamma * d * d);
      float a = hf[(g0 + nn) * 160 + 64 + t * 3 + 0] * uS[nn][0]
              + hf[(g0 + nn) * 160 + 64 + t * 3 + 1] * uS[nn][1]
              + hf[(g0 + nn) * 160 + 64 + t * 3 + 2] * uS[nn][2];
      xvu[(g0 + nn) * 32 + t] = a;
    }
  }
  if (t < 96) {
    #pragma unroll
    for (int nn = 0; nn < 2; ++nn) {
      const int g = g0 + nn;
      if (t < 64) {
        invn[nn][t] = hf[g * 160 + t];
      } else {
        int o = t - 64;
        float v0 = hf[g * 160 + 64 + o * 3 + 0];
        float v1 = hf[g * 160 + 64 + o * 3 + 1];
        float v2 = hf[g * 160 + 64 + o * 3 + 2];
        invn[nn][t] = sqrtf((v0 * v0 + v1 * v1 + v2 * v2) * (1.0f / 3.0f) + 1e-8f);
      }
    }
  }
  if (t < 2) {
    const int n = (g0 + t) & 63;
    float r = rS[t];
    float cw = 0.0f;
    if (r <= 6.0f && n != 0) cw = 0.5f * (cosf(PIF * r * (1.0f / 6.0f)) + 1.0f);
    y1cw[(g0 + t) * 4 + 0] = SQRT3F * uS[t][0];
    y1cw[(g0 + t) * 4 + 1] = SQRT3F * uS[t][1];
    y1cw[(g0 + t) * 4 + 2] = SQRT3F * uS[t][2];
    y1cw[(g0 + t) * 4 + 3] = cw;
  }
  __syncthreads();

  {
    float a0 = vwb0[t], a1 = a0;
    #pragma unroll 8
    for (int k = 0; k < 64; ++k) {
      float w = vwW0[k * 128 + t];
      a0 = fmaf(vin[0][k], w, a0);
      a1 = fmaf(vin[1][k], w, a1);
    }
    h0[0][t] = silu_f(a0); h0[1][t] = silu_f(a1);
  }
  __syncthreads();
  {
    float a0 = vwb1[t], a1 = a0;
    #pragma unroll 8
    for (int k = 0; k < 128; ++k) {
      float w = vwW1[k * 128 + t];
      a0 = fmaf(h0[0][k], w, a0);
      a1 = fmaf(h0[1][k], w, a1);
    }
    float hv[2] = {silu_f(a0), silu_f(a1)};
    #pragma unroll
    for (int nn = 0; nn < 2; ++nn) {
      unsigned short hh = f2bf(hv[nn]);
      hTh[(size_t)(g0 + nn) * 128 + t] = hh;
      hTl[(size_t)(g0 + nn) * 128 + t] = f2bf(hv[nn] - bf2f(hh));
    }
  }
  {
    float p0 = 0.f, p1 = 0.f;
    #pragma unroll 8
    for (int k = 0; k < 96; ++k) {
      float w = scW0[(96 + k) * 128 + t];
      p0 = fmaf(invn[0][k], w, p0);
      p1 = fmaf(invn[1][k], w, p1);
    }
    #pragma unroll 8
    for (int k = 0; k < 64; ++k) {
      float w = scW0[(192 + k) * 128 + t];
      p0 = fmaf(vin[0][k], w, p0);
      p1 = fmaf(vin[1][k], w, p1);
    }
    Pn[(g0 + 0) * 128 + t] = p0;
    Pn[(g0 + 1) * 128 + t] = p1;
  }
  if ((g0 & 63) == 0) {
    float p = 0.0f;
    #pragma unroll 8
    for (int k = 0; k < 96; ++k) p = fmaf(invn[0][k], scW0[k * 128 + t], p);
    Pa[b * 128 + t] = p;
  }
}

// ---------------------------------------------------------------------------
// KPe: Pe[e][t] = sc_b0[t] + e_feat[e]@We. grid=128, block=128.
// ---------------------------------------------------------------------------
__global__ void k_pe(const float* __restrict__ e_feat, const float* __restrict__ scW0,
                     const float* __restrict__ scb0, float* __restrict__ Pe) {
  const int e = blockIdx.x;
  const int t = threadIdx.x;
  float a = scb0[t];
  #pragma unroll
  for (int k = 0; k < 16; ++k) a = fmaf(e_feat[e * 16 + k], scW0[(256 + k) * 128 + t], a);
  Pe[e * 128 + t] = a;
}

// ---------------------------------------------------------------------------
// K2 v12: MFMA GEMM + register contraction, canonical LDS-B pipeline.
// (unchanged from R12 — out of top-5)
// ---------------------------------------------------------------------------
__device__ __forceinline__ int tile_of(int cs, int t) {
  if (t < 8)  return cs * 8 + t;
  if (t < 12) return 256 + cs * 4 + (t - 8);
  if (t < 14) return 384 + cs * 2 + (t - 12);
  return 448 + cs * 4 + (t - 14);
}

__global__ void __launch_bounds__(256) k_tp(
    const unsigned short* __restrict__ hTh, const unsigned short* __restrict__ hTl,
    const unsigned short* __restrict__ W2fh, const unsigned short* __restrict__ W2fl,
    const float* __restrict__ b2, const float* __restrict__ hf,
    const float* __restrict__ xvu, const float* __restrict__ y1cw,
    float* __restrict__ values8) {
  const int bid = blockIdx.x;
  const int cs = bid & 31;
  const int g0 = (bid >> 5) * 64;
  const int p8 = cs & 7;
  const int tid = threadIdx.x;
  const int w = tid >> 6, l = tid & 63;
  const int q = l >> 4, cq = l & 15;

  __shared__ unsigned short BstH[2][256][8];
  __shared__ unsigned short BstL[2][256][8];
  __shared__ float valsS[64][160];
  __shared__ float svS[64][32];

  for (int idx = tid; idx < 64 * 160; idx += 256) ((float*)valsS)[idx] = 0.f;
  for (int idx = tid; idx < 64 * 32; idx += 256) ((float*)svS)[idx] = 0.f;

  const int anode = g0 + w * 16 + cq;
  v8s ah0 = *(const v8s*)&hTh[(size_t)anode * 128 + 0 * 32 + q * 8];
  v8s ah1 = *(const v8s*)&hTh[(size_t)anode * 128 + 1 * 32 + q * 8];
  v8s ah2 = *(const v8s*)&hTh[(size_t)anode * 128 + 2 * 32 + q * 8];
  v8s ah3 = *(const v8s*)&hTh[(size_t)anode * 128 + 3 * 32 + q * 8];
  v8s al0 = *(const v8s*)&hTl[(size_t)anode * 128 + 0 * 32 + q * 8];
  v8s al1 = *(const v8s*)&hTl[(size_t)anode * 128 + 1 * 32 + q * 8];
  v8s al2 = *(const v8s*)&hTl[(size_t)anode * 128 + 2 * 32 + q * 8];
  v8s al3 = *(const v8s*)&hTl[(size_t)anode * 128 + 3 * 32 + q * 8];

  float racc1[4][4] = {{0.f}};
  float racc2[2][4] = {{0.f}};
  float racc3[2][4][3] = {{{0.f}}};
  float racc4[4][4] = {{0.f}};

  const int nrow = w * 16 + q * 4;

  {
    const int T = tile_of(cs, 0);
    uint4 gh = *(const uint4*)&W2fh[(size_t)T * 2048 + tid * 8];
    uint4 gl = *(const uint4*)&W2fl[(size_t)T * 2048 + tid * 8];
    *(uint4*)&BstH[0][tid][0] = gh;
    *(uint4*)&BstL[0][tid][0] = gl;
  }
  __syncthreads();

  #pragma unroll
  for (int t = 0; t < 18; ++t) {
    const int buf = t & 1;
    uint4 gh, gl;
    if (t < 17) {
      const int Tn = tile_of(cs, t + 1);
      gh = *(const uint4*)&W2fh[(size_t)Tn * 2048 + tid * 8];
      gl = *(const uint4*)&W2fl[(size_t)Tn * 2048 + tid * 8];
    }

    const int T = tile_of(cs, t);
    v8s bh0 = *(const v8s*)&BstH[buf][0 * 64 + l][0];
    v8s bh1 = *(const v8s*)&BstH[buf][1 * 64 + l][0];
    v8s bh2 = *(const v8s*)&BstH[buf][2 * 64 + l][0];
    v8s bh3 = *(const v8s*)&BstH[buf][3 * 64 + l][0];
    v8s bl0 = *(const v8s*)&BstL[buf][0 * 64 + l][0];
    v8s bl1 = *(const v8s*)&BstL[buf][1 * 64 + l][0];
    v8s bl2 = *(const v8s*)&BstL[buf][2 * 64 + l][0];
    v8s bl3 = *(const v8s*)&BstL[buf][3 * 64 + l][0];

    v4f a0 = (v4f){0.f, 0.f, 0.f, 0.f};
    v4f a1 = (v4f){0.f, 0.f, 0.f, 0.f};
    v4f a2 = (v4f){0.f, 0.f, 0.f, 0.f};
    a0 = __builtin_amdgcn_mfma_f32_16x16x32_bf16(ah0, bh0, a0, 0, 0, 0);
    a1 = __builtin_amdgcn_mfma_f32_16x16x32_bf16(al0, bh0, a1, 0, 0, 0);
    a2 = __builtin_amdgcn_mfma_f32_16x16x32_bf16(ah0, bl0, a2, 0, 0, 0);
    a0 = __builtin_amdgcn_mfma_f32_16x16x32_bf16(ah1, bh1, a0, 0, 0, 0);
    a1 = __builtin_amdgcn_mfma_f32_16x16x32_bf16(al1, bh1, a1, 0, 0, 0);
    a2 = __builtin_amdgcn_mfma_f32_16x16x32_bf16(ah1, bl1, a2, 0, 0, 0);
    a0 = __builtin_amdgcn_mfma_f32_16x16x32_bf16(ah2, bh2, a0, 0, 0, 0);
    a1 = __builtin_amdgcn_mfma_f32_16x16x32_bf16(al2, bh2, a1, 0, 0, 0);
    a2 = __builtin_amdgcn_mfma_f32_16x16x32_bf16(ah2, bl2, a2, 0, 0, 0);
    a0 = __builtin_amdgcn_mfma_f32_16x16x32_bf16(ah3, bh3, a0, 0, 0, 0);
    a1 = __builtin_amdgcn_mfma_f32_16x16x32_bf16(al3, bh3, a1, 0, 0, 0);
    a2 = __builtin_amdgcn_mfma_f32_16x16x32_bf16(ah3, bl3, a2, 0, 0, 0);
    a0 += a1; a0 += a2;
    const float bj = b2[T * 16 + cq];
    v4f tp = a0;
    tp[0] += bj; tp[1] += bj; tp[2] += bj; tp[3] += bj;

    if (t < 8) {
      const int i = cs * 2 + (t >> 2);
      const int m = t & 3;
      #pragma unroll
      for (int r = 0; r < 4; ++r)
        racc1[m][r] = fmaf(hf[(size_t)(g0 + nrow + r) * 160 + i], tp[r], racc1[m][r]);
    } else if (t < 12) {
      const int i = cs * 2 + ((t - 8) >> 1);
      const int m = (t - 8) & 1;
      #pragma unroll
      for (int r = 0; r < 4; ++r)
        racc2[m][r] = fmaf(hf[(size_t)(g0 + nrow + r) * 160 + i], tp[r], racc2[m][r]);
    } else if (t < 14) {
      const int m = (t - 12) & 1;
      #pragma unroll
      for (int r = 0; r < 4; ++r) {
        const float* xvp = hf + (size_t)(g0 + nrow + r) * 160 + 64 + 3 * cs;
        #pragma unroll
        for (int cc = 0; cc < 3; ++cc)
          racc3[m][r][cc] = fmaf(xvp[cc], tp[r], racc3[m][r][cc]);
      }
    } else {
      const int m = (t - 14) & 3;
      #pragma unroll
      for (int r = 0; r < 4; ++r)
        racc4[m][r] = fmaf(xvu[(size_t)(g0 + nrow + r) * 32 + cs], tp[r], racc4[m][r]);
    }

    if (t < 17) {
      const int nbuf = buf ^ 1;
      *(uint4*)&BstH[nbuf][tid][0] = gh;
      *(uint4*)&BstL[nbuf][tid][0] = gl;
    }
    __syncthreads();
  }

  #pragma unroll
  for (int r = 0; r < 4; ++r) {
    const int n = nrow + r;
    #pragma unroll
    for (int m = 0; m < 4; ++m)
      valsS[n][m * 16 + cq] += racc1[m][r] + racc4[m][r];
    #pragma unroll
    for (int m = 0; m < 2; ++m)
      svS[n][m * 16 + cq] += racc2[m][r];
    #pragma unroll
    for (int m = 0; m < 2; ++m)
      #pragma unroll
      for (int cc = 0; cc < 3; ++cc)
        valsS[n][64 + 3 * (m * 16 + cq) + cc] += racc3[m][r][cc];
  }
  __syncthreads();

  float* vtgt = values8 + (size_t)p8 * 163840;
  const float* y1b = y1cw + (size_t)g0 * 4;
  for (int idx = tid; idx < 10240; idx += 256) {
    int n = idx / 160, d = idx - n * 160;
    float v = valsS[n][d];
    if (d >= 64) {
      int dd = d - 64, o = dd / 3, cc = dd - 3 * o;
      v = fmaf(svS[n][o], y1b[n * 4 + cc], v);
    }
    atomicAdd(&vtgt[(size_t)(g0 + n) * 160 + d], v);
  }
}

// ---------------------------------------------------------------------------
// K2b: values[n][d] = ALPHAF * sum_p values8[p][n][d]. grid=160, block=256.
// ---------------------------------------------------------------------------
__global__ void __launch_bounds__(256) k_reduce(
    const float* __restrict__ values8, float* __restrict__ values) {
  const int s = blockIdx.x * 256 + threadIdx.x;
  float4 acc = make_float4(0.f, 0.f, 0.f, 0.f);
  #pragma unroll
  for (int p = 0; p < 8; ++p) {
    float4 v = *(const float4*)&values8[(size_t)p * 163840 + s * 4];
    acc.x += v.x; acc.y += v.y; acc.z += v.z; acc.w += v.w;
  }
  acc.x *= ALPHAF; acc.y *= ALPHAF; acc.z *= ALPHAF; acc.w *= ALPHAF;
  *(float4*)&values[(size_t)s * 4] = acc;
}

// ---------------------------------------------------------------------------
// K3 v4: MFMA gate MLP + aggregation per (b,e). grid=2048, block=256.
// ---------------------------------------------------------------------------
__global__ void __launch_bounds__(256, 4) k_gate_agg(
    const float* __restrict__ Pa, const float* __restrict__ Pe,
    const float* __restrict__ Pn,
    const unsigned short* __restrict__ W1fh, const unsigned short* __restrict__ W1fl,
    const float* __restrict__ b1, const float* __restrict__ W2v,
    const float* __restrict__ b2s, const float* __restrict__ y1cw,
    const float* __restrict__ values, float* __restrict__ inv_agg) {
  const int bid = blockIdx.x;
  const int b = bid >> 7, e = bid & 127;
  const int tid = threadIdx.x;

  __shared__ float Prow[128];
  __shared__ float gpre[64];
  __shared__ float gateL[64];
  __shared__ float aggL[160];
  __shared__ float normS;

  if (tid < 128) Prow[tid] = Pa[b * 128 + tid] + Pe[e * 128 + tid];
  __syncthreads();

  const int w = tid >> 6, l = tid & 63;
  const int q = l >> 4, cq = l & 15;
  const int node = w * 16 + cq;
  const float* pnrow = Pn + (size_t)(b * 64 + node) * 128;

  v4f acc[8];
  #pragma unroll
  for (int t = 0; t < 8; ++t) acc[t] = (v4f){0.f, 0.f, 0.f, 0.f};

  #pragma unroll
  for (int ks = 0; ks < 4; ++ks) {
    const int k0 = ks * 32 + q * 8;
    float4 p0 = *(const float4*)(pnrow + k0);
    float4 p1 = *(const float4*)(pnrow + k0 + 4);
    float4 r0 = *(const float4*)(&Prow[k0]);
    float4 r1 = *(const float4*)(&Prow[k0 + 4]);
    float xv[8] = {p0.x + r0.x, p0.y + r0.y, p0.z + r0.z, p0.w + r0.w,
                   p1.x + r1.x, p1.y + r1.y, p1.z + r1.z, p1.w + r1.w};
    v8s avh, avl;
    #pragma unroll
    for (int j = 0; j < 8; ++j) {
      float x = silu_f(xv[j]);
      unsigned short h = f2bf(x);
      avh[j] = (short)h;
      avl[j] = (short)f2bf(x - bf2f(h));
    }
    #pragma unroll
    for (int t = 0; t < 8; ++t) {
      const size_t fb = (size_t)((ks * 8 + t) * 64 + l) * 8;
      v8s bh = *(const v8s*)&W1fh[fb];
      v8s bl = *(const v8s*)&W1fl[fb];
      acc[t] = __builtin_amdgcn_mfma_f32_16x16x32_bf16(avh, bh, acc[t], 0, 0, 0);
      acc[t] = __builtin_amdgcn_mfma_f32_16x16x32_bf16(avl, bh, acc[t], 0, 0, 0);
      acc[t] = __builtin_amdgcn_mfma_f32_16x16x32_bf16(avh, bl, acc[t], 0, 0, 0);
    }
  }

  float part0 = 0.f, part1 = 0.f, part2 = 0.f, part3 = 0.f;
  #pragma unroll
  for (int t = 0; t < 8; ++t) {
    float bb = b1[t * 16 + cq];
    float wg = W2v[t * 16 + cq];
    part0 = fmaf(silu_f(acc[t][0] + bb), wg, part0);
    part1 = fmaf(silu_f(acc[t][1] + bb), wg, part1);
    part2 = fmaf(silu_f(acc[t][2] + bb), wg, part2);
    part3 = fmaf(silu_f(acc[t][3] + bb), wg, part3);
  }
  #pragma unroll
  for (int off = 1; off < 16; off <<= 1) {
    part0 += __shfl_xor(part0, off);
    part1 += __shfl_xor(part1, off);
    part2 += __shfl_xor(part2, off);
    part3 += __shfl_xor(part3, off);
  }
  if (cq == 0) {
    gpre[w * 16 + q * 4 + 0] = part0;
    gpre[w * 16 + q * 4 + 1] = part1;
    gpre[w * 16 + q * 4 + 2] = part2;
    gpre[w * 16 + q * 4 + 3] = part3;
  }
  __syncthreads();

  if (tid < 64) {
    float gv = sigmoid_f(gpre[tid] + b2s[0]);
    gv *= y1cw[(b * 64 + tid) * 4 + 3];
    gateL[tid] = gv;
    float t2 = gv;
    #pragma unroll
    for (int off = 32; off > 0; off >>= 1) t2 += __shfl_down(t2, off);
    if (tid == 0) normS = fmaxf(t2, 1e-8f);
  }
  __syncthreads();

  if (tid < 160) {
    float a = 0.0f;
    const float* vp = values + (size_t)b * 64 * 160 + tid;
    #pragma unroll 4
    for (int n = 0; n < 64; ++n) a = fmaf(gateL[n], vp[n * 160], a);
    aggL[tid] = a / normS;
  }
  __syncthreads();
  if (tid < 96) {
    float rv;
    if (tid < 64) {
      rv = aggL[tid];
    } else {
      int o = tid - 64;
      float a0 = aggL[64 + o * 3 + 0];
      float a1 = aggL[64 + o * 3 + 1];
      float a2 = aggL[64 + o * 3 + 2];
      rv = sqrtf((a0 * a0 + a1 * a1 + a2 * a2) * (1.0f / 3.0f) + 1e-8f);
    }
    inv_agg[bid * 96 + tid] = rv;
  }
}

// ---------------------------------------------------------------------------
// K4 v2: FUSED out-MLP (96->128 silu, 128->128 silu, 128->128) via MFMA.
// grid = 128 blocks x 16 rows; wave w owns output cols [w*32, w*32+32).
// A-frags cast in-register; h1/h2 round-trip through one 16x132 LDS tile.
// Replaces three latency-bound k_mlp launches (R12: 3 x ~50us, VALU 1.3%).
// ---------------------------------------------------------------------------
__global__ void __launch_bounds__(256) k_out(
    const float* __restrict__ X,
    const unsigned short* __restrict__ O0h, const unsigned short* __restrict__ O0l,
    const unsigned short* __restrict__ O1h, const unsigned short* __restrict__ O1l,
    const unsigned short* __restrict__ O2h, const unsigned short* __restrict__ O2l,
    const float* __restrict__ b0, const float* __restrict__ b1,
    const float* __restrict__ b2, float* __restrict__ out) {
  const int r0 = blockIdx.x * 16;
  const int tid = threadIdx.x;
  const int w = tid >> 6, l = tid & 63;
  const int q = l >> 4, cq = l & 15;
  const int t0 = 2 * w, t1 = 2 * w + 1;

  __shared__ float hS[16][132];

  // ---- layer 1: K=96, A from X(invagg) ----
  v4f acc0 = (v4f){0.f, 0.f, 0.f, 0.f};
  v4f acc1 = (v4f){0.f, 0.f, 0.f, 0.f};
  {
    const float* xrow = X + (size_t)(r0 + cq) * 96 + q * 8;
    #pragma unroll
    for (int ks = 0; ks < 3; ++ks) {
      float4 p0 = *(const float4*)(xrow + ks * 32);
      float4 p1 = *(const float4*)(xrow + ks * 32 + 4);
      float xv[8] = {p0.x, p0.y, p0.z, p0.w, p1.x, p1.y, p1.z, p1.w};
      v8s avh, avl;
      #pragma unroll
      for (int j = 0; j < 8; ++j) {
        unsigned short h = f2bf(xv[j]);
        avh[j] = (short)h;
        avl[j] = (short)f2bf(xv[j] - bf2f(h));
      }
      v8s b0h = *(const v8s*)&O0h[((size_t)(ks * 8 + t0) * 64 + l) * 8];
      v8s b0l = *(const v8s*)&O0l[((size_t)(ks * 8 + t0) * 64 + l) * 8];
      v8s b1h = *(const v8s*)&O0h[((size_t)(ks * 8 + t1) * 64 + l) * 8];
      v8s b1l = *(const v8s*)&O0l[((size_t)(ks * 8 + t1) * 64 + l) * 8];
      acc0 = __builtin_amdgcn_mfma_f32_16x16x32_bf16(avh, b0h, acc0, 0, 0, 0);
      acc0 = __builtin_amdgcn_mfma_f32_16x16x32_bf16(avl, b0h, acc0, 0, 0, 0);
      acc0 = __builtin_amdgcn_mfma_f32_16x16x32_bf16(avh, b0l, acc0, 0, 0, 0);
      acc1 = __builtin_amdgcn_mfma_f32_16x16x32_bf16(avh, b1h, acc1, 0, 0, 0);
      acc1 = __builtin_amdgcn_mfma_f32_16x16x32_bf16(avl, b1h, acc1, 0, 0, 0);
      acc1 = __builtin_amdgcn_mfma_f32_16x16x32_bf16(avh, b1l, acc1, 0, 0, 0);
    }
  }
  {
    const float bb0 = b0[t0 * 16 + cq], bb1 = b0[t1 * 16 + cq];
    #pragma unroll
    for (int r = 0; r < 4; ++r) {
      hS[q * 4 + r][t0 * 16 + cq] = silu_f(acc0[r] + bb0);
      hS[q * 4 + r][t1 * 16 + cq] = silu_f(acc1[r] + bb1);
    }
  }
  __syncthreads();

  // ---- layer 2: K=128, A from hS ----
  v8s a2h[4], a2l[4];
  #pragma unroll
  for (int ks = 0; ks < 4; ++ks) {
    float4 p0 = *(const float4*)&hS[cq][ks * 32 + q * 8];
    float4 p1 = *(const float4*)&hS[cq][ks * 32 + q * 8 + 4];
    float xv[8] = {p0.x, p0.y, p0.z, p0.w, p1.x, p1.y, p1.z, p1.w};
    #pragma unroll
    for (int j = 0; j < 8; ++j) {
      unsigned short h = f2bf(xv[j]);
      a2h[ks][j] = (short)h;
      a2l[ks][j] = (short)f2bf(xv[j] - bf2f(h));
    }
  }
  __syncthreads();   // all reads of hS done
  acc0 = (v4f){0.f, 0.f, 0.f, 0.f};
  acc1 = (v4f){0.f, 0.f, 0.f, 0.f};
  #pragma unroll
  for (int ks = 0; ks < 4; ++ks) {
    v8s b0h = *(const v8s*)&O1h[((size_t)(ks * 8 + t0) * 64 + l) * 8];
    v8s b0l = *(const v8s*)&O1l[((size_t)(ks * 8 + t0) * 64 + l) * 8];
    v8s b1h = *(const v8s*)&O1h[((size_t)(ks * 8 + t1) * 64 + l) * 8];
    v8s b1l = *(const v8s*)&O1l[((size_t)(ks * 8 + t1) * 64 + l) * 8];
    acc0 = __builtin_amdgcn_mfma_f32_16x16x32_bf16(a2h[ks], b0h, acc0, 0, 0, 0);
    acc0 = __builtin_amdgcn_mfma_f32_16x16x32_bf16(a2l[ks], b0h, acc0, 0, 0, 0);
    acc0 = __builtin_amdgcn_mfma_f32_16x16x32_bf16(a2h[ks], b0l, acc0, 0, 0, 0);
    acc1 = __builtin_amdgcn_mfma_f32_16x16x32_bf16(a2h[ks], b1h, acc1, 0, 0, 0);
    acc1 = __builtin_amdgcn_mfma_f32_16x16x32_bf16(a2l[ks], b1h, acc1, 0, 0, 0);
    acc1 = __builtin_amdgcn_mfma_f32_16x16x32_bf16(a2h[ks], b1l, acc1, 0, 0, 0);
  }
  {
    const float bb0 = b1[t0 * 16 + cq], bb1 = b1[t1 * 16 + cq];
    #pragma unroll
    for (int r = 0; r < 4; ++r) {
      hS[q * 4 + r][t0 * 16 + cq] = silu_f(acc0[r] + bb0);
      hS[q * 4 + r][t1 * 16 + cq] = silu_f(acc1[r] + bb1);
    }
  }
  __syncthreads();

  // ---- layer 3: K=128, A from hS, no act ----
  #pragma unroll
  for (int ks = 0; ks < 4; ++ks) {
    float4 p0 = *(const float4*)&hS[cq][ks * 32 + q * 8];
    float4 p1 = *(const float4*)&hS[cq][ks * 32 + q * 8 + 4];
    float xv[8] = {p0.x, p0.y, p0.z, p0.w, p1.x, p1.y, p1.z, p1.w};
    #pragma unroll
    for (int j = 0; j < 8; ++j) {
      unsigned short h = f2bf(xv[j]);
      a2h[ks][j] = (short)h;
      a2l[ks][j] = (short)f2bf(xv[j] - bf2f(h));
    }
  }
  acc0 = (v4f){0.f, 0.f, 0.f, 0.f};
  acc1 = (v4f){0.f, 0.f, 0.f, 0.f};
  #pragma unroll
  for (int ks = 0; ks < 4; ++ks) {
    v8s b0h = *(const v8s*)&O2h[((size_t)(ks * 8 + t0) * 64 + l) * 8];
    v8s b0l = *(const v8s*)&O2l[((size_t)(ks * 8 + t0) * 64 + l) * 8];
    v8s b1h = *(const v8s*)&O2h[((size_t)(ks * 8 + t1) * 64 + l) * 8];
    v8s b1l = *(const v8s*)&O2l[((size_t)(ks * 8 + t1) * 64 + l) * 8];
    acc0 = __builtin_amdgcn_mfma_f32_16x16x32_bf16(a2h[ks], b0h, acc0, 0, 0, 0);
    acc0 = __builtin_amdgcn_mfma_f32_16x16x32_bf16(a2l[ks], b0h, acc0, 0, 0, 0);
    acc0 = __builtin_amdgcn_mfma_f32_16x16x32_bf16(a2h[ks], b0l, acc0, 0, 0, 0);
    acc1 = __builtin_amdgcn_mfma_f32_16x16x32_bf16(a2h[ks], b1h, acc1, 0, 0, 0);
    acc1 = __builtin_amdgcn_mfma_f32_16x16x32_bf16(a2l[ks], b1h, acc1, 0, 0, 0);
    acc1 = __builtin_amdgcn_mfma_f32_16x16x32_bf16(a2h[ks], b1l, acc1, 0, 0, 0);
  }
  {
    const float bb0 = b2[t0 * 16 + cq], bb1 = b2[t1 * 16 + cq];
    #pragma unroll
    for (int r = 0; r < 4; ++r) {
      out[(size_t)(r0 + q * 4 + r) * 128 + t0 * 16 + cq] = acc0[r] + bb0;
      out[(size_t)(r0 + q * 4 + r) * 128 + t1 * 16 + cq] = acc1[r] + bb1;
    }
  }
}

// ---------------------------------------------------------------------------
extern "C" void kernel_launch(void* const* d_in, const int* in_sizes, int n_in,
                              void* d_out, int out_size, void* d_ws, size_t ws_size,
                              hipStream_t stream) {
  const float* hf    = (const float*)d_in[0];
  const int*   z     = (const int*)  d_in[1];
  const float* pos   = (const float*)d_in[2];
  const float* e_feat= (const float*)d_in[4];
  const float* z_emb = (const float*)d_in[5];
  const float* vwW0  = (const float*)d_in[6];
  const float* vwb0  = (const float*)d_in[7];
  const float* vwW1  = (const float*)d_in[8];
  const float* vwb1  = (const float*)d_in[9];
  const float* vwW2  = (const float*)d_in[10];
  const float* vwb2  = (const float*)d_in[11];
  const float* scW0  = (const float*)d_in[12];
  const float* scb0  = (const float*)d_in[13];
  const float* scW1  = (const float*)d_in[14];
  const float* scb1  = (const float*)d_in[15];
  const float* scW2  = (const float*)d_in[16];
  const float* scb2  = (const float*)d_in[17];
  const float* oW0   = (const float*)d_in[18];
  const float* ob0   = (const float*)d_in[19];
  const float* oW1   = (const float*)d_in[20];
  const float* ob1   = (const float*)d_in[21];
  const float* oW2   = (const float*)d_in[22];
  const float* ob2   = (const float*)d_in[23];
  float* out = (float*)d_out;

  float* ws = (float*)d_ws;
  unsigned short* W2fh = (unsigned short*)(ws);            // 589824 fl
  unsigned short* W2fl = (unsigned short*)(ws + 589824);   // 589824 fl
  unsigned short* hTh  = (unsigned short*)(ws + 1179648);  // 65536 fl
  unsigned short* hTl  = (unsigned short*)(ws + 1245184);  // 65536 fl
  float* Pn     = ws + 1310720;   // 131072
  float* Pa     = Pn + 131072;    // 2048
  float* Pe     = Pa + 2048;      // 16384
  float* xvu    = Pe + 16384;     // 32768
  float* y1cw   = xvu + 32768;    // 4096
  float* values = y1cw + 4096;    // 163840
  float* invagg = values + 163840;// 196608
  unsigned short* W1fh = (unsigned short*)(invagg + 196608);  // 8192 fl
  unsigned short* W1fl = (unsigned short*)(invagg + 196608 + 8192);
  float* values8 = invagg + 196608 + 16384;  // 8*163840 fl
  // out-MLP packs alias the W2f region (dead after k_tp):
  unsigned short* Ob = (unsigned short*)ws;
  unsigned short* O0h = Ob;               // 1536*8
  unsigned short* O0l = Ob + 12288;
  unsigned short* O1h = Ob + 24576;       // 2048*8
  unsigned short* O1l = Ob + 40960;
  unsigned short* O2h = Ob + 57344;
  unsigned short* O2l = Ob + 73728;       // ends 90112 u16

  hipMemsetAsync(values8, 0, 8 * 163840 * sizeof(float), stream);

  k_castw2<<<576, 256, 0, stream>>>(vwW2, W2fh, W2fl);
  k_castw1<<<8, 256, 0, stream>>>(scW1, W1fh, W1fl);
  k_prep<<<512, 128, 0, stream>>>(hf, z, pos, z_emb, vwW0, vwb0, vwW1, vwb1,
                                  scW0, hTh, hTl, Pn, Pa, xvu, y1cw);
  k_pe<<<128, 128, 0, stream>>>(e_feat, scW0, scb0, Pe);
  k_tp<<<512, 256, 0, stream>>>(hTh, hTl, W2fh, W2fl, vwb2, hf, xvu,
                                y1cw, values8);
  k_packout<<<22, 256, 0, stream>>>(oW0, oW1, oW2, O0h, O0l, O1h, O1l, O2h, O2l);
  k_reduce<<<160, 256, 0, stream>>>(values8, values);
  k_gate_agg<<<2048, 256, 0, stream>>>(Pa, Pe, Pn, W1fh, W1fl, scb1, scW2, scb2,
                                       y1cw, values, invagg);
  k_out<<<128, 256, 0, stream>>>(invagg, O0h, O0l, O1h, O1l, O2h, O2l,
                                 ob0, ob1, ob2, out);
}

// Round 14
// 217.848 us; speedup vs baseline: 1.7137x; 1.0287x over previous
//
#include <hip/hip_runtime.h>
#include <hip/hip_bf16.h>
#include <math.h>

// Sizes: B=16, N=64, nE=128, H=128, LAT=128, NS=64, NV=32, INV=96, D_NODE=160
#define SQRT3F 1.7320508075688772f
#define ALPHAF 0.10206207261596577f  // 1/sqrt(96)
#define PIF 3.14159265358979323846f

typedef short v8s __attribute__((ext_vector_type(8)));
typedef float v4f __attribute__((ext_vector_type(4)));

__device__ __forceinline__ float silu_f(float x) {
  return x / (1.0f + __expf(-x));
}
__device__ __forceinline__ float sigmoid_f(float x) {
  return 1.0f / (1.0f + __expf(-x));
}
__device__ __forceinline__ unsigned short f2bf(float f) {
  unsigned int u = __float_as_uint(f);
  unsigned int r = (u + 0x7fffu + ((u >> 16) & 1u)) >> 16;
  return (unsigned short)r;
}
__device__ __forceinline__ float bf2f(unsigned short h) {
  return __uint_as_float(((unsigned int)h) << 16);
}
// truncation split: ~5 VALU instr vs ~12 for double-rounded. h=RTZ(x),
// l=RTZ(x-h). Missing ll-term + l-truncation ~2^-16 rel — safe vs threshold.
__device__ __forceinline__ void split_trunc(float x, short* h, short* l) {
  unsigned int u = __float_as_uint(x);
  unsigned short hs = (unsigned short)(u >> 16);
  float r = x - __uint_as_float((unsigned int)hs << 16);
  *h = (short)hs;
  *l = (short)(__float_as_uint(r) >> 16);
}

// ---------------------------------------------------------------------------
// K-1: cast W2 (128 x 9216 fp32) into MFMA B-FRAGMENT order, bf16 hi/lo.
// ---------------------------------------------------------------------------
__global__ void __launch_bounds__(256) k_castw2(
    const float* __restrict__ W2, unsigned short* __restrict__ W2fh,
    unsigned short* __restrict__ W2fl) {
  const int T = blockIdx.x;           // column tile of 16
  const int tid = threadIdx.x;
  __shared__ float Tl[128][17];

  for (int idx = tid; idx < 2048; idx += 256) {
    int k = idx >> 4, cc = idx & 15;
    Tl[k][cc] = W2[(size_t)k * 9216 + T * 16 + cc];
  }
  __syncthreads();

  const int ks = tid >> 6, lane = tid & 63;
  const int q = lane >> 4, cq = lane & 15;
  const int k0 = ks * 32 + q * 8;
  unsigned short hv[8], lv[8];
  #pragma unroll
  for (int j = 0; j < 8; ++j) {
    float wv = Tl[k0 + j][cq];
    unsigned short h = f2bf(wv);
    hv[j] = h;
    lv[j] = f2bf(wv - bf2f(h));
  }
  size_t base = ((size_t)(T * 4 + ks) * 64 + lane) * 8;
  *(uint4*)&W2fh[base] = *(uint4*)hv;
  *(uint4*)&W2fl[base] = *(uint4*)lv;
}

// ---------------------------------------------------------------------------
// K-2: pack sc_W1 (128x128) into MFMA B-fragment order, bf16 hi/lo.
// ---------------------------------------------------------------------------
__global__ void __launch_bounds__(256) k_castw1(
    const float* __restrict__ W1, unsigned short* __restrict__ W1fh,
    unsigned short* __restrict__ W1fl) {
  const int s = blockIdx.x * 256 + threadIdx.x;   // 0..2047
  const int lane = s & 63;
  const int t = (s >> 6) & 7;
  const int ks = s >> 9;
  const int kbase = ks * 32 + (lane >> 4) * 8;
  const int n = t * 16 + (lane & 15);
  unsigned short hv[8], lv[8];
  #pragma unroll
  for (int j = 0; j < 8; ++j) {
    float w = W1[(size_t)(kbase + j) * 128 + n];
    unsigned short h = f2bf(w);
    hv[j] = h;
    lv[j] = f2bf(w - bf2f(h));
  }
  *(uint4*)&W1fh[(size_t)s * 8] = *(uint4*)hv;
  *(uint4*)&W1fl[(size_t)s * 8] = *(uint4*)lv;
}

// ---------------------------------------------------------------------------
// K-3: pack out-MLP weights into B-fragment bf16 hi/lo. grid=22.
// ---------------------------------------------------------------------------
__global__ void __launch_bounds__(256) k_packout(
    const float* __restrict__ W0, const float* __restrict__ W1,
    const float* __restrict__ W2,
    unsigned short* __restrict__ O0h, unsigned short* __restrict__ O0l,
    unsigned short* __restrict__ O1h, unsigned short* __restrict__ O1l,
    unsigned short* __restrict__ O2h, unsigned short* __restrict__ O2l) {
  const int s = blockIdx.x * 256 + threadIdx.x;   // 0..5631
  if (s >= 5632) return;
  const float* W; unsigned short *fh, *fl; int s0;
  if (s < 1536)      { W = W0; fh = O0h; fl = O0l; s0 = s; }
  else if (s < 3584) { W = W1; fh = O1h; fl = O1l; s0 = s - 1536; }
  else               { W = W2; fh = O2h; fl = O2l; s0 = s - 3584; }
  const int lane = s0 & 63;
  const int t = (s0 >> 6) & 7;
  const int ks = s0 >> 9;
  const int kbase = ks * 32 + (lane >> 4) * 8;
  const int n = t * 16 + (lane & 15);
  unsigned short hv[8], lv[8];
  #pragma unroll
  for (int j = 0; j < 8; ++j) {
    float w = W[(size_t)(kbase + j) * 128 + n];
    unsigned short h = f2bf(w);
    hv[j] = h;
    lv[j] = f2bf(w - bf2f(h));
  }
  *(uint4*)&fh[(size_t)s0 * 8] = *(uint4*)hv;
  *(uint4*)&fl[(size_t)s0 * 8] = *(uint4*)lv;
}

// ---------------------------------------------------------------------------
// K0 v3: per-node prep, 2 nodes per block. grid=512, block=128.
// ---------------------------------------------------------------------------
__global__ void k_prep(const float* __restrict__ hf, const int* __restrict__ z,
                       const float* __restrict__ pos, const float* __restrict__ z_emb,
                       const float* __restrict__ vwW0, const float* __restrict__ vwb0,
                       const float* __restrict__ vwW1, const float* __restrict__ vwb1,
                       const float* __restrict__ scW0,
                       unsigned short* __restrict__ hTh, unsigned short* __restrict__ hTl,
                       float* __restrict__ Pn, float* __restrict__ Pa,
                       float* __restrict__ xvu, float* __restrict__ y1cw) {
  const int g0 = blockIdx.x * 2;
  const int b = g0 >> 6;
  const int t = threadIdx.x;

  __shared__ float vin[2][64];
  __shared__ float invn[2][96];
  __shared__ float h0[2][128];
  __shared__ float uS[2][3];
  __shared__ float rS[2];

  if (t < 2) {
    const int g = g0 + t;
    float px = pos[g * 3 + 0] - pos[(b * 64) * 3 + 0];
    float py = pos[g * 3 + 1] - pos[(b * 64) * 3 + 1];
    float pz = pos[g * 3 + 2] - pos[(b * 64) * 3 + 2];
    float r = sqrtf(px * px + py * py + pz * pz + 1e-12f);
    float rm = fmaxf(r, 1e-8f);
    uS[t][0] = px / rm; uS[t][1] = py / rm; uS[t][2] = pz / rm;
    rS[t] = r;
  }
  __syncthreads();

  if (t < 32) {
    const float delta = 6.0f / 31.0f;
    const float gamma = 1.0f / (delta * delta + 1e-12f);
    #pragma unroll
    for (int nn = 0; nn < 2; ++nn) {
      int zi = z[g0 + nn];
      vin[nn][t] = z_emb[zi * 32 + t];
      float rc = fminf(rS[nn], 6.0f);
      float d = rc - (float)t * delta;
      vin[nn][32 + t] = __expf(-gamma * d * d);
      float a = hf[(g0 + nn) * 160 + 64 + t * 3 + 0] * uS[nn][0]
              + hf[(g0 + nn) * 160 + 64 + t * 3 + 1] * uS[nn][1]
              + hf[(g0 + nn) * 160 + 64 + t * 3 + 2] * uS[nn][2];
      xvu[(g0 + nn) * 32 + t] = a;
    }
  }
  if (t < 96) {
    #pragma unroll
    for (int nn = 0; nn < 2; ++nn) {
      const int g = g0 + nn;
      if (t < 64) {
        invn[nn][t] = hf[g * 160 + t];
      } else {
        int o = t - 64;
        float v0 = hf[g * 160 + 64 + o * 3 + 0];
        float v1 = hf[g * 160 + 64 + o * 3 + 1];
        float v2 = hf[g * 160 + 64 + o * 3 + 2];
        invn[nn][t] = sqrtf((v0 * v0 + v1 * v1 + v2 * v2) * (1.0f / 3.0f) + 1e-8f);
      }
    }
  }
  if (t < 2) {
    const int n = (g0 + t) & 63;
    float r = rS[t];
    float cw = 0.0f;
    if (r <= 6.0f && n != 0) cw = 0.5f * (cosf(PIF * r * (1.0f / 6.0f)) + 1.0f);
    y1cw[(g0 + t) * 4 + 0] = SQRT3F * uS[t][0];
    y1cw[(g0 + t) * 4 + 1] = SQRT3F * uS[t][1];
    y1cw[(g0 + t) * 4 + 2] = SQRT3F * uS[t][2];
    y1cw[(g0 + t) * 4 + 3] = cw;
  }
  __syncthreads();

  {
    float a0 = vwb0[t], a1 = a0;
    #pragma unroll 8
    for (int k = 0; k < 64; ++k) {
      float w = vwW0[k * 128 + t];
      a0 = fmaf(vin[0][k], w, a0);
      a1 = fmaf(vin[1][k], w, a1);
    }
    h0[0][t] = silu_f(a0); h0[1][t] = silu_f(a1);
  }
  __syncthreads();
  {
    float a0 = vwb1[t], a1 = a0;
    #pragma unroll 8
    for (int k = 0; k < 128; ++k) {
      float w = vwW1[k * 128 + t];
      a0 = fmaf(h0[0][k], w, a0);
      a1 = fmaf(h0[1][k], w, a1);
    }
    float hv[2] = {silu_f(a0), silu_f(a1)};
    #pragma unroll
    for (int nn = 0; nn < 2; ++nn) {
      unsigned short hh = f2bf(hv[nn]);
      hTh[(size_t)(g0 + nn) * 128 + t] = hh;
      hTl[(size_t)(g0 + nn) * 128 + t] = f2bf(hv[nn] - bf2f(hh));
    }
  }
  {
    float p0 = 0.f, p1 = 0.f;
    #pragma unroll 8
    for (int k = 0; k < 96; ++k) {
      float w = scW0[(96 + k) * 128 + t];
      p0 = fmaf(invn[0][k], w, p0);
      p1 = fmaf(invn[1][k], w, p1);
    }
    #pragma unroll 8
    for (int k = 0; k < 64; ++k) {
      float w = scW0[(192 + k) * 128 + t];
      p0 = fmaf(vin[0][k], w, p0);
      p1 = fmaf(vin[1][k], w, p1);
    }
    Pn[(g0 + 0) * 128 + t] = p0;
    Pn[(g0 + 1) * 128 + t] = p1;
  }
  if ((g0 & 63) == 0) {
    float p = 0.0f;
    #pragma unroll 8
    for (int k = 0; k < 96; ++k) p = fmaf(invn[0][k], scW0[k * 128 + t], p);
    Pa[b * 128 + t] = p;
  }
}

// ---------------------------------------------------------------------------
// KPe: Pe[e][t] = sc_b0[t] + e_feat[e]@We. grid=128, block=128.
// ---------------------------------------------------------------------------
__global__ void k_pe(const float* __restrict__ e_feat, const float* __restrict__ scW0,
                     const float* __restrict__ scb0, float* __restrict__ Pe) {
  const int e = blockIdx.x;
  const int t = threadIdx.x;
  float a = scb0[t];
  #pragma unroll
  for (int k = 0; k < 16; ++k) a = fmaf(e_feat[e * 16 + k], scW0[(256 + k) * 128 + t], a);
  Pe[e * 128 + t] = a;
}

// ---------------------------------------------------------------------------
// K2 v12: MFMA GEMM + register contraction, canonical LDS-B pipeline.
// ---------------------------------------------------------------------------
__device__ __forceinline__ int tile_of(int cs, int t) {
  if (t < 8)  return cs * 8 + t;
  if (t < 12) return 256 + cs * 4 + (t - 8);
  if (t < 14) return 384 + cs * 2 + (t - 12);
  return 448 + cs * 4 + (t - 14);
}

__global__ void __launch_bounds__(256) k_tp(
    const unsigned short* __restrict__ hTh, const unsigned short* __restrict__ hTl,
    const unsigned short* __restrict__ W2fh, const unsigned short* __restrict__ W2fl,
    const float* __restrict__ b2, const float* __restrict__ hf,
    const float* __restrict__ xvu, const float* __restrict__ y1cw,
    float* __restrict__ values8) {
  const int bid = blockIdx.x;
  const int cs = bid & 31;
  const int g0 = (bid >> 5) * 64;
  const int p8 = cs & 7;
  const int tid = threadIdx.x;
  const int w = tid >> 6, l = tid & 63;
  const int q = l >> 4, cq = l & 15;

  __shared__ unsigned short BstH[2][256][8];
  __shared__ unsigned short BstL[2][256][8];
  __shared__ float valsS[64][160];
  __shared__ float svS[64][32];

  for (int idx = tid; idx < 64 * 160; idx += 256) ((float*)valsS)[idx] = 0.f;
  for (int idx = tid; idx < 64 * 32; idx += 256) ((float*)svS)[idx] = 0.f;

  const int anode = g0 + w * 16 + cq;
  v8s ah0 = *(const v8s*)&hTh[(size_t)anode * 128 + 0 * 32 + q * 8];
  v8s ah1 = *(const v8s*)&hTh[(size_t)anode * 128 + 1 * 32 + q * 8];
  v8s ah2 = *(const v8s*)&hTh[(size_t)anode * 128 + 2 * 32 + q * 8];
  v8s ah3 = *(const v8s*)&hTh[(size_t)anode * 128 + 3 * 32 + q * 8];
  v8s al0 = *(const v8s*)&hTl[(size_t)anode * 128 + 0 * 32 + q * 8];
  v8s al1 = *(const v8s*)&hTl[(size_t)anode * 128 + 1 * 32 + q * 8];
  v8s al2 = *(const v8s*)&hTl[(size_t)anode * 128 + 2 * 32 + q * 8];
  v8s al3 = *(const v8s*)&hTl[(size_t)anode * 128 + 3 * 32 + q * 8];

  float racc1[4][4] = {{0.f}};
  float racc2[2][4] = {{0.f}};
  float racc3[2][4][3] = {{{0.f}}};
  float racc4[4][4] = {{0.f}};

  const int nrow = w * 16 + q * 4;

  {
    const int T = tile_of(cs, 0);
    uint4 gh = *(const uint4*)&W2fh[(size_t)T * 2048 + tid * 8];
    uint4 gl = *(const uint4*)&W2fl[(size_t)T * 2048 + tid * 8];
    *(uint4*)&BstH[0][tid][0] = gh;
    *(uint4*)&BstL[0][tid][0] = gl;
  }
  __syncthreads();

  #pragma unroll
  for (int t = 0; t < 18; ++t) {
    const int buf = t & 1;
    uint4 gh, gl;
    if (t < 17) {
      const int Tn = tile_of(cs, t + 1);
      gh = *(const uint4*)&W2fh[(size_t)Tn * 2048 + tid * 8];
      gl = *(const uint4*)&W2fl[(size_t)Tn * 2048 + tid * 8];
    }

    const int T = tile_of(cs, t);
    v8s bh0 = *(const v8s*)&BstH[buf][0 * 64 + l][0];
    v8s bh1 = *(const v8s*)&BstH[buf][1 * 64 + l][0];
    v8s bh2 = *(const v8s*)&BstH[buf][2 * 64 + l][0];
    v8s bh3 = *(const v8s*)&BstH[buf][3 * 64 + l][0];
    v8s bl0 = *(const v8s*)&BstL[buf][0 * 64 + l][0];
    v8s bl1 = *(const v8s*)&BstL[buf][1 * 64 + l][0];
    v8s bl2 = *(const v8s*)&BstL[buf][2 * 64 + l][0];
    v8s bl3 = *(const v8s*)&BstL[buf][3 * 64 + l][0];

    v4f a0 = (v4f){0.f, 0.f, 0.f, 0.f};
    v4f a1 = (v4f){0.f, 0.f, 0.f, 0.f};
    v4f a2 = (v4f){0.f, 0.f, 0.f, 0.f};
    a0 = __builtin_amdgcn_mfma_f32_16x16x32_bf16(ah0, bh0, a0, 0, 0, 0);
    a1 = __builtin_amdgcn_mfma_f32_16x16x32_bf16(al0, bh0, a1, 0, 0, 0);
    a2 = __builtin_amdgcn_mfma_f32_16x16x32_bf16(ah0, bl0, a2, 0, 0, 0);
    a0 = __builtin_amdgcn_mfma_f32_16x16x32_bf16(ah1, bh1, a0, 0, 0, 0);
    a1 = __builtin_amdgcn_mfma_f32_16x16x32_bf16(al1, bh1, a1, 0, 0, 0);
    a2 = __builtin_amdgcn_mfma_f32_16x16x32_bf16(ah1, bl1, a2, 0, 0, 0);
    a0 = __builtin_amdgcn_mfma_f32_16x16x32_bf16(ah2, bh2, a0, 0, 0, 0);
    a1 = __builtin_amdgcn_mfma_f32_16x16x32_bf16(al2, bh2, a1, 0, 0, 0);
    a2 = __builtin_amdgcn_mfma_f32_16x16x32_bf16(ah2, bl2, a2, 0, 0, 0);
    a0 = __builtin_amdgcn_mfma_f32_16x16x32_bf16(ah3, bh3, a0, 0, 0, 0);
    a1 = __builtin_amdgcn_mfma_f32_16x16x32_bf16(al3, bh3, a1, 0, 0, 0);
    a2 = __builtin_amdgcn_mfma_f32_16x16x32_bf16(ah3, bl3, a2, 0, 0, 0);
    a0 += a1; a0 += a2;
    const float bj = b2[T * 16 + cq];
    v4f tp = a0;
    tp[0] += bj; tp[1] += bj; tp[2] += bj; tp[3] += bj;

    if (t < 8) {
      const int i = cs * 2 + (t >> 2);
      const int m = t & 3;
      #pragma unroll
      for (int r = 0; r < 4; ++r)
        racc1[m][r] = fmaf(hf[(size_t)(g0 + nrow + r) * 160 + i], tp[r], racc1[m][r]);
    } else if (t < 12) {
      const int i = cs * 2 + ((t - 8) >> 1);
      const int m = (t - 8) & 1;
      #pragma unroll
      for (int r = 0; r < 4; ++r)
        racc2[m][r] = fmaf(hf[(size_t)(g0 + nrow + r) * 160 + i], tp[r], racc2[m][r]);
    } else if (t < 14) {
      const int m = (t - 12) & 1;
      #pragma unroll
      for (int r = 0; r < 4; ++r) {
        const float* xvp = hf + (size_t)(g0 + nrow + r) * 160 + 64 + 3 * cs;
        #pragma unroll
        for (int cc = 0; cc < 3; ++cc)
          racc3[m][r][cc] = fmaf(xvp[cc], tp[r], racc3[m][r][cc]);
      }
    } else {
      const int m = (t - 14) & 3;
      #pragma unroll
      for (int r = 0; r < 4; ++r)
        racc4[m][r] = fmaf(xvu[(size_t)(g0 + nrow + r) * 32 + cs], tp[r], racc4[m][r]);
    }

    if (t < 17) {
      const int nbuf = buf ^ 1;
      *(uint4*)&BstH[nbuf][tid][0] = gh;
      *(uint4*)&BstL[nbuf][tid][0] = gl;
    }
    __syncthreads();
  }

  #pragma unroll
  for (int r = 0; r < 4; ++r) {
    const int n = nrow + r;
    #pragma unroll
    for (int m = 0; m < 4; ++m)
      valsS[n][m * 16 + cq] += racc1[m][r] + racc4[m][r];
    #pragma unroll
    for (int m = 0; m < 2; ++m)
      svS[n][m * 16 + cq] += racc2[m][r];
    #pragma unroll
    for (int m = 0; m < 2; ++m)
      #pragma unroll
      for (int cc = 0; cc < 3; ++cc)
        valsS[n][64 + 3 * (m * 16 + cq) + cc] += racc3[m][r][cc];
  }
  __syncthreads();

  float* vtgt = values8 + (size_t)p8 * 163840;
  const float* y1b = y1cw + (size_t)g0 * 4;
  for (int idx = tid; idx < 10240; idx += 256) {
    int n = idx / 160, d = idx - n * 160;
    float v = valsS[n][d];
    if (d >= 64) {
      int dd = d - 64, o = dd / 3, cc = dd - 3 * o;
      v = fmaf(svS[n][o], y1b[n * 4 + cc], v);
    }
    atomicAdd(&vtgt[(size_t)(g0 + n) * 160 + d], v);
  }
}

// ---------------------------------------------------------------------------
// K2b: values[n][d] = ALPHAF * sum_p values8[p][n][d]. grid=160, block=256.
// ---------------------------------------------------------------------------
__global__ void __launch_bounds__(256) k_reduce(
    const float* __restrict__ values8, float* __restrict__ values) {
  const int s = blockIdx.x * 256 + threadIdx.x;
  float4 acc = make_float4(0.f, 0.f, 0.f, 0.f);
  #pragma unroll
  for (int p = 0; p < 8; ++p) {
    float4 v = *(const float4*)&values8[(size_t)p * 163840 + s * 4];
    acc.x += v.x; acc.y += v.y; acc.z += v.z; acc.w += v.w;
  }
  acc.x *= ALPHAF; acc.y *= ALPHAF; acc.z *= ALPHAF; acc.w *= ALPHAF;
  *(float4*)&values[(size_t)s * 4] = acc;
}

// ---------------------------------------------------------------------------
// K3 v5: MFMA gate MLP + aggregation, TWO energies per block. grid=1024.
// Each W1-fragment load feeds 6 MFMAs (was 3); each values load feeds 2 fma;
// truncation split (~5 instr vs ~12). b = bid>>6, e0 = (bid&63)*2.
// ---------------------------------------------------------------------------
__global__ void __launch_bounds__(256, 4) k_gate_agg(
    const float* __restrict__ Pa, const float* __restrict__ Pe,
    const float* __restrict__ Pn,
    const unsigned short* __restrict__ W1fh, const unsigned short* __restrict__ W1fl,
    const float* __restrict__ b1, const float* __restrict__ W2v,
    const float* __restrict__ b2s, const float* __restrict__ y1cw,
    const float* __restrict__ values, float* __restrict__ inv_agg) {
  const int bid = blockIdx.x;
  const int b = bid >> 6;
  const int e0 = (bid & 63) * 2, e1 = e0 + 1;
  const int tid = threadIdx.x;

  __shared__ float Prow0[128], Prow1[128];
  __shared__ float gpre[2][64];
  __shared__ float gateL[2][64];
  __shared__ float aggL[2][160];
  __shared__ float normS[2];

  if (tid < 128) {
    float pa = Pa[b * 128 + tid];
    Prow0[tid] = pa + Pe[e0 * 128 + tid];
    Prow1[tid] = pa + Pe[e1 * 128 + tid];
  }
  __syncthreads();

  const int w = tid >> 6, l = tid & 63;
  const int q = l >> 4, cq = l & 15;
  const int node = w * 16 + cq;
  const float* pnrow = Pn + (size_t)(b * 64 + node) * 128;

  v4f acc0[8], acc1[8];
  #pragma unroll
  for (int t = 0; t < 8; ++t) {
    acc0[t] = (v4f){0.f, 0.f, 0.f, 0.f};
    acc1[t] = (v4f){0.f, 0.f, 0.f, 0.f};
  }

  #pragma unroll
  for (int ks = 0; ks < 4; ++ks) {
    const int k0 = ks * 32 + q * 8;
    float4 p0 = *(const float4*)(pnrow + k0);
    float4 p1 = *(const float4*)(pnrow + k0 + 4);
    float pv[8] = {p0.x, p0.y, p0.z, p0.w, p1.x, p1.y, p1.z, p1.w};
    float4 r00 = *(const float4*)(&Prow0[k0]);
    float4 r01 = *(const float4*)(&Prow0[k0 + 4]);
    float4 r10 = *(const float4*)(&Prow1[k0]);
    float4 r11 = *(const float4*)(&Prow1[k0 + 4]);
    float rv0[8] = {r00.x, r00.y, r00.z, r00.w, r01.x, r01.y, r01.z, r01.w};
    float rv1[8] = {r10.x, r10.y, r10.z, r10.w, r11.x, r11.y, r11.z, r11.w};
    v8s a0h, a0l, a1h, a1l;
    #pragma unroll
    for (int j = 0; j < 8; ++j) {
      short hs, ls;
      split_trunc(silu_f(pv[j] + rv0[j]), &hs, &ls);
      a0h[j] = hs; a0l[j] = ls;
      split_trunc(silu_f(pv[j] + rv1[j]), &hs, &ls);
      a1h[j] = hs; a1l[j] = ls;
    }
    #pragma unroll
    for (int t = 0; t < 8; ++t) {
      const size_t fb = (size_t)((ks * 8 + t) * 64 + l) * 8;
      v8s bh = *(const v8s*)&W1fh[fb];
      v8s bl = *(const v8s*)&W1fl[fb];
      acc0[t] = __builtin_amdgcn_mfma_f32_16x16x32_bf16(a0h, bh, acc0[t], 0, 0, 0);
      acc0[t] = __builtin_amdgcn_mfma_f32_16x16x32_bf16(a0l, bh, acc0[t], 0, 0, 0);
      acc0[t] = __builtin_amdgcn_mfma_f32_16x16x32_bf16(a0h, bl, acc0[t], 0, 0, 0);
      acc1[t] = __builtin_amdgcn_mfma_f32_16x16x32_bf16(a1h, bh, acc1[t], 0, 0, 0);
      acc1[t] = __builtin_amdgcn_mfma_f32_16x16x32_bf16(a1l, bh, acc1[t], 0, 0, 0);
      acc1[t] = __builtin_amdgcn_mfma_f32_16x16x32_bf16(a1h, bl, acc1[t], 0, 0, 0);
    }
  }

  float p00 = 0.f, p01 = 0.f, p02 = 0.f, p03 = 0.f;
  float p10 = 0.f, p11 = 0.f, p12 = 0.f, p13 = 0.f;
  #pragma unroll
  for (int t = 0; t < 8; ++t) {
    float bb = b1[t * 16 + cq];
    float wg = W2v[t * 16 + cq];
    p00 = fmaf(silu_f(acc0[t][0] + bb), wg, p00);
    p01 = fmaf(silu_f(acc0[t][1] + bb), wg, p01);
    p02 = fmaf(silu_f(acc0[t][2] + bb), wg, p02);
    p03 = fmaf(silu_f(acc0[t][3] + bb), wg, p03);
    p10 = fmaf(silu_f(acc1[t][0] + bb), wg, p10);
    p11 = fmaf(silu_f(acc1[t][1] + bb), wg, p11);
    p12 = fmaf(silu_f(acc1[t][2] + bb), wg, p12);
    p13 = fmaf(silu_f(acc1[t][3] + bb), wg, p13);
  }
  #pragma unroll
  for (int off = 1; off < 16; off <<= 1) {
    p00 += __shfl_xor(p00, off); p01 += __shfl_xor(p01, off);
    p02 += __shfl_xor(p02, off); p03 += __shfl_xor(p03, off);
    p10 += __shfl_xor(p10, off); p11 += __shfl_xor(p11, off);
    p12 += __shfl_xor(p12, off); p13 += __shfl_xor(p13, off);
  }
  if (cq == 0) {
    gpre[0][w * 16 + q * 4 + 0] = p00;
    gpre[0][w * 16 + q * 4 + 1] = p01;
    gpre[0][w * 16 + q * 4 + 2] = p02;
    gpre[0][w * 16 + q * 4 + 3] = p03;
    gpre[1][w * 16 + q * 4 + 0] = p10;
    gpre[1][w * 16 + q * 4 + 1] = p11;
    gpre[1][w * 16 + q * 4 + 2] = p12;
    gpre[1][w * 16 + q * 4 + 3] = p13;
  }
  __syncthreads();

  if (tid < 128) {
    const int ee = tid >> 6, ll = tid & 63;
    float gv = sigmoid_f(gpre[ee][ll] + b2s[0]);
    gv *= y1cw[(b * 64 + ll) * 4 + 3];
    gateL[ee][ll] = gv;
    float t2 = gv;
    #pragma unroll
    for (int off = 32; off > 0; off >>= 1) t2 += __shfl_down(t2, off);
    if (ll == 0) normS[ee] = fmaxf(t2, 1e-8f);
  }
  __syncthreads();

  if (tid < 160) {
    float a0 = 0.0f, a1 = 0.0f;
    const float* vp = values + (size_t)b * 64 * 160 + tid;
    #pragma unroll 4
    for (int n = 0; n < 64; ++n) {
      float v = vp[n * 160];
      a0 = fmaf(gateL[0][n], v, a0);
      a1 = fmaf(gateL[1][n], v, a1);
    }
    aggL[0][tid] = a0 / normS[0];
    aggL[1][tid] = a1 / normS[1];
  }
  __syncthreads();
  if (tid < 192) {
    const int ee = tid < 96 ? 0 : 1;
    const int ll = tid < 96 ? tid : tid - 96;
    const int e = ee == 0 ? e0 : e1;
    const float* ag = aggL[ee];
    float rv;
    if (ll < 64) {
      rv = ag[ll];
    } else {
      int o = ll - 64;
      float a0 = ag[64 + o * 3 + 0];
      float a1 = ag[64 + o * 3 + 1];
      float a2 = ag[64 + o * 3 + 2];
      rv = sqrtf((a0 * a0 + a1 * a1 + a2 * a2) * (1.0f / 3.0f) + 1e-8f);
    }
    inv_agg[(size_t)(b * 128 + e) * 96 + ll] = rv;
  }
}

// ---------------------------------------------------------------------------
// K4 v2: FUSED out-MLP (96->128 silu, 128->128 silu, 128->128) via MFMA.
// ---------------------------------------------------------------------------
__global__ void __launch_bounds__(256) k_out(
    const float* __restrict__ X,
    const unsigned short* __restrict__ O0h, const unsigned short* __restrict__ O0l,
    const unsigned short* __restrict__ O1h, const unsigned short* __restrict__ O1l,
    const unsigned short* __restrict__ O2h, const unsigned short* __restrict__ O2l,
    const float* __restrict__ b0, const float* __restrict__ b1,
    const float* __restrict__ b2, float* __restrict__ out) {
  const int r0 = blockIdx.x * 16;
  const int tid = threadIdx.x;
  const int w = tid >> 6, l = tid & 63;
  const int q = l >> 4, cq = l & 15;
  const int t0 = 2 * w, t1 = 2 * w + 1;

  __shared__ float hS[16][132];

  v4f acc0 = (v4f){0.f, 0.f, 0.f, 0.f};
  v4f acc1 = (v4f){0.f, 0.f, 0.f, 0.f};
  {
    const float* xrow = X + (size_t)(r0 + cq) * 96 + q * 8;
    #pragma unroll
    for (int ks = 0; ks < 3; ++ks) {
      float4 p0 = *(const float4*)(xrow + ks * 32);
      float4 p1 = *(const float4*)(xrow + ks * 32 + 4);
      float xv[8] = {p0.x, p0.y, p0.z, p0.w, p1.x, p1.y, p1.z, p1.w};
      v8s avh, avl;
      #pragma unroll
      for (int j = 0; j < 8; ++j) {
        unsigned short h = f2bf(xv[j]);
        avh[j] = (short)h;
        avl[j] = (short)f2bf(xv[j] - bf2f(h));
      }
      v8s b0h = *(const v8s*)&O0h[((size_t)(ks * 8 + t0) * 64 + l) * 8];
      v8s b0l = *(const v8s*)&O0l[((size_t)(ks * 8 + t0) * 64 + l) * 8];
      v8s b1h = *(const v8s*)&O0h[((size_t)(ks * 8 + t1) * 64 + l) * 8];
      v8s b1l = *(const v8s*)&O0l[((size_t)(ks * 8 + t1) * 64 + l) * 8];
      acc0 = __builtin_amdgcn_mfma_f32_16x16x32_bf16(avh, b0h, acc0, 0, 0, 0);
      acc0 = __builtin_amdgcn_mfma_f32_16x16x32_bf16(avl, b0h, acc0, 0, 0, 0);
      acc0 = __builtin_amdgcn_mfma_f32_16x16x32_bf16(avh, b0l, acc0, 0, 0, 0);
      acc1 = __builtin_amdgcn_mfma_f32_16x16x32_bf16(avh, b1h, acc1, 0, 0, 0);
      acc1 = __builtin_amdgcn_mfma_f32_16x16x32_bf16(avl, b1h, acc1, 0, 0, 0);
      acc1 = __builtin_amdgcn_mfma_f32_16x16x32_bf16(avh, b1l, acc1, 0, 0, 0);
    }
  }
  {
    const float bb0 = b0[t0 * 16 + cq], bb1 = b0[t1 * 16 + cq];
    #pragma unroll
    for (int r = 0; r < 4; ++r) {
      hS[q * 4 + r][t0 * 16 + cq] = silu_f(acc0[r] + bb0);
      hS[q * 4 + r][t1 * 16 + cq] = silu_f(acc1[r] + bb1);
    }
  }
  __syncthreads();

  v8s a2h[4], a2l[4];
  #pragma unroll
  for (int ks = 0; ks < 4; ++ks) {
    float4 p0 = *(const float4*)&hS[cq][ks * 32 + q * 8];
    float4 p1 = *(const float4*)&hS[cq][ks * 32 + q * 8 + 4];
    float xv[8] = {p0.x, p0.y, p0.z, p0.w, p1.x, p1.y, p1.z, p1.w};
    #pragma unroll
    for (int j = 0; j < 8; ++j) {
      unsigned short h = f2bf(xv[j]);
      a2h[ks][j] = (short)h;
      a2l[ks][j] = (short)f2bf(xv[j] - bf2f(h));
    }
  }
  __syncthreads();
  acc0 = (v4f){0.f, 0.f, 0.f, 0.f};
  acc1 = (v4f){0.f, 0.f, 0.f, 0.f};
  #pragma unroll
  for (int ks = 0; ks < 4; ++ks) {
    v8s b0h = *(const v8s*)&O1h[((size_t)(ks * 8 + t0) * 64 + l) * 8];
    v8s b0l = *(const v8s*)&O1l[((size_t)(ks * 8 + t0) * 64 + l) * 8];
    v8s b1h = *(const v8s*)&O1h[((size_t)(ks * 8 + t1) * 64 + l) * 8];
    v8s b1l = *(const v8s*)&O1l[((size_t)(ks * 8 + t1) * 64 + l) * 8];
    acc0 = __builtin_amdgcn_mfma_f32_16x16x32_bf16(a2h[ks], b0h, acc0, 0, 0, 0);
    acc0 = __builtin_amdgcn_mfma_f32_16x16x32_bf16(a2l[ks], b0h, acc0, 0, 0, 0);
    acc0 = __builtin_amdgcn_mfma_f32_16x16x32_bf16(a2h[ks], b0l, acc0, 0, 0, 0);
    acc1 = __builtin_amdgcn_mfma_f32_16x16x32_bf16(a2h[ks], b1h, acc1, 0, 0, 0);
    acc1 = __builtin_amdgcn_mfma_f32_16x16x32_bf16(a2l[ks], b1h, acc1, 0, 0, 0);
    acc1 = __builtin_amdgcn_mfma_f32_16x16x32_bf16(a2h[ks], b1l, acc1, 0, 0, 0);
  }
  {
    const float bb0 = b1[t0 * 16 + cq], bb1 = b1[t1 * 16 + cq];
    #pragma unroll
    for (int r = 0; r < 4; ++r) {
      hS[q * 4 + r][t0 * 16 + cq] = silu_f(acc0[r] + bb0);
      hS[q * 4 + r][t1 * 16 + cq] = silu_f(acc1[r] + bb1);
    }
  }
  __syncthreads();

  #pragma unroll
  for (int ks = 0; ks < 4; ++ks) {
    float4 p0 = *(const float4*)&hS[cq][ks * 32 + q * 8];
    float4 p1 = *(const float4*)&hS[cq][ks * 32 + q * 8 + 4];
    float xv[8] = {p0.x, p0.y, p0.z, p0.w, p1.x, p1.y, p1.z, p1.w};
    #pragma unroll
    for (int j = 0; j < 8; ++j) {
      unsigned short h = f2bf(xv[j]);
      a2h[ks][j] = (short)h;
      a2l[ks][j] = (short)f2bf(xv[j] - bf2f(h));
    }
  }
  acc0 = (v4f){0.f, 0.f, 0.f, 0.f};
  acc1 = (v4f){0.f, 0.f, 0.f, 0.f};
  #pragma unroll
  for (int ks = 0; ks < 4; ++ks) {
    v8s b0h = *(const v8s*)&O2h[((size_t)(ks * 8 + t0) * 64 + l) * 8];
    v8s b0l = *(const v8s*)&O2l[((size_t)(ks * 8 + t0) * 64 + l) * 8];
    v8s b1h = *(const v8s*)&O2h[((size_t)(ks * 8 + t1) * 64 + l) * 8];
    v8s b1l = *(const v8s*)&O2l[((size_t)(ks * 8 + t1) * 64 + l) * 8];
    acc0 = __builtin_amdgcn_mfma_f32_16x16x32_bf16(a2h[ks], b0h, acc0, 0, 0, 0);
    acc0 = __builtin_amdgcn_mfma_f32_16x16x32_bf16(a2l[ks], b0h, acc0, 0, 0, 0);
    acc0 = __builtin_amdgcn_mfma_f32_16x16x32_bf16(a2h[ks], b0l, acc0, 0, 0, 0);
    acc1 = __builtin_amdgcn_mfma_f32_16x16x32_bf16(a2h[ks], b1h, acc1, 0, 0, 0);
    acc1 = __builtin_amdgcn_mfma_f32_16x16x32_bf16(a2l[ks], b1h, acc1, 0, 0, 0);
    acc1 = __builtin_amdgcn_mfma_f32_16x16x32_bf16(a2h[ks], b1l, acc1, 0, 0, 0);
  }
  {
    const float bb0 = b2[t0 * 16 + cq], bb1 = b2[t1 * 16 + cq];
    #pragma unroll
    for (int r = 0; r < 4; ++r) {
      out[(size_t)(r0 + q * 4 + r) * 128 + t0 * 16 + cq] = acc0[r] + bb0;
      out[(size_t)(r0 + q * 4 + r) * 128 + t1 * 16 + cq] = acc1[r] + bb1;
    }
  }
}

// ---------------------------------------------------------------------------
extern "C" void kernel_launch(void* const* d_in, const int* in_sizes, int n_in,
                              void* d_out, int out_size, void* d_ws, size_t ws_size,
                              hipStream_t stream) {
  const float* hf    = (const float*)d_in[0];
  const int*   z     = (const int*)  d_in[1];
  const float* pos   = (const float*)d_in[2];
  const float* e_feat= (const float*)d_in[4];
  const float* z_emb = (const float*)d_in[5];
  const float* vwW0  = (const float*)d_in[6];
  const float* vwb0  = (const float*)d_in[7];
  const float* vwW1  = (const float*)d_in[8];
  const float* vwb1  = (const float*)d_in[9];
  const float* vwW2  = (const float*)d_in[10];
  const float* vwb2  = (const float*)d_in[11];
  const float* scW0  = (const float*)d_in[12];
  const float* scb0  = (const float*)d_in[13];
  const float* scW1  = (const float*)d_in[14];
  const float* scb1  = (const float*)d_in[15];
  const float* scW2  = (const float*)d_in[16];
  const float* scb2  = (const float*)d_in[17];
  const float* oW0   = (const float*)d_in[18];
  const float* ob0   = (const float*)d_in[19];
  const float* oW1   = (const float*)d_in[20];
  const float* ob1   = (const float*)d_in[21];
  const float* oW2   = (const float*)d_in[22];
  const float* ob2   = (const float*)d_in[23];
  float* out = (float*)d_out;

  float* ws = (float*)d_ws;
  unsigned short* W2fh = (unsigned short*)(ws);            // 589824 fl
  unsigned short* W2fl = (unsigned short*)(ws + 589824);   // 589824 fl
  unsigned short* hTh  = (unsigned short*)(ws + 1179648);  // 65536 fl
  unsigned short* hTl  = (unsigned short*)(ws + 1245184);  // 65536 fl
  float* Pn     = ws + 1310720;   // 131072
  float* Pa     = Pn + 131072;    // 2048
  float* Pe     = Pa + 2048;      // 16384
  float* xvu    = Pe + 16384;     // 32768
  float* y1cw   = xvu + 32768;    // 4096
  float* values = y1cw + 4096;    // 163840
  float* invagg = values + 163840;// 196608
  unsigned short* W1fh = (unsigned short*)(invagg + 196608);  // 8192 fl
  unsigned short* W1fl = (unsigned short*)(invagg + 196608 + 8192);
  float* values8 = invagg + 196608 + 16384;  // 8*163840 fl
  unsigned short* Ob = (unsigned short*)ws;
  unsigned short* O0h = Ob;
  unsigned short* O0l = Ob + 12288;
  unsigned short* O1h = Ob + 24576;
  unsigned short* O1l = Ob + 40960;
  unsigned short* O2h = Ob + 57344;
  unsigned short* O2l = Ob + 73728;

  hipMemsetAsync(values8, 0, 8 * 163840 * sizeof(float), stream);

  k_castw2<<<576, 256, 0, stream>>>(vwW2, W2fh, W2fl);
  k_castw1<<<8, 256, 0, stream>>>(scW1, W1fh, W1fl);
  k_prep<<<512, 128, 0, stream>>>(hf, z, pos, z_emb, vwW0, vwb0, vwW1, vwb1,
                                  scW0, hTh, hTl, Pn, Pa, xvu, y1cw);
  k_pe<<<128, 128, 0, stream>>>(e_feat, scW0, scb0, Pe);
  k_tp<<<512, 256, 0, stream>>>(hTh, hTl, W2fh, W2fl, vwb2, hf, xvu,
                                y1cw, values8);
  k_packout<<<22, 256, 0, stream>>>(oW0, oW1, oW2, O0h, O0l, O1h, O1l, O2h, O2l);
  k_reduce<<<160, 256, 0, stream>>>(values8, values);
  k_gate_agg<<<1024, 256, 0, stream>>>(Pa, Pe, Pn, W1fh, W1fl, scb1, scW2, scb2,
                                       y1cw, values, invagg);
  k_out<<<128, 256, 0, stream>>>(invagg, O0h, O0l, O1h, O1l, O2h, O2l,
                                 ob0, ob1, ob2, out);
}